// Round 4
// baseline (795.323 us; speedup 1.0000x reference)
//
#include <hip/hip_runtime.h>
#include <cstdint>
#include <cstddef>

#define BSZ 2
#define NV 16
#define SEQ 1024
#define DIM 768
#define VOC 50257
#define VOCP 50304   // padded to multiple of 128

typedef unsigned int u32;
typedef unsigned short u16;
typedef _Float16 half8 __attribute__((ext_vector_type(8)));
typedef float f32x4 __attribute__((ext_vector_type(4)));

__device__ __forceinline__ u16 f2h(float f) {
  return __builtin_bit_cast(unsigned short, (_Float16)f);
}
__device__ __forceinline__ u32 pk2h(float a, float b) {
  return (u32)f2h(a) | ((u32)f2h(b) << 16);
}

// async global->LDS, 16B per lane; LDS dest = wave-uniform base + lane*16
__device__ __forceinline__ void gload16(const u16* g, u16* l) {
  __builtin_amdgcn_global_load_lds(
      (const __attribute__((address_space(1))) void*)g,
      (__attribute__((address_space(3))) void*)l, 16, 0, 0);
}

// ---------------------------------------------------------------------------
// K1: content f32 -> f16 (normal + transposed per (b,k) slice)
__global__ void k_prep_content(const float* __restrict__ content,
                               u16* __restrict__ cbf, u16* __restrict__ cT) {
  __shared__ u16 tile[32][33];
  const int bk = blockIdx.z;
  const int d0 = blockIdx.x * 32, j0 = blockIdx.y * 32;
  const float* src = content + (size_t)bk * SEQ * DIM;
  u16* dst = cbf + (size_t)bk * SEQ * DIM;
  u16* dstT = cT + (size_t)bk * DIM * SEQ;
  const int c = threadIdx.x;
#pragma unroll
  for (int rr = 0; rr < 4; ++rr) {
    const int r = threadIdx.y * 4 + rr;
    const float v = src[(size_t)(j0 + r) * DIM + d0 + c];
    const u16 bv = f2h(v);
    dst[(size_t)(j0 + r) * DIM + d0 + c] = bv;
    tile[r][c] = bv;
  }
  __syncthreads();
#pragma unroll
  for (int rr = 0; rr < 4; ++rr) {
    const int r = threadIdx.y * 4 + rr;       // d-local
    dstT[(size_t)(d0 + r) * SEQ + j0 + c] = tile[c][r];
  }
}

// K2: lm_head_weight f32 -> f16, padded rows zeroed. grid VOCP, block 192
__global__ void k_prep_w(const float* __restrict__ W, u16* __restrict__ Wb) {
  const int v = blockIdx.x;
  const int c = threadIdx.x * 4;
  u32 lo, hi;
  if (v < VOC) {
    const float4 f = *(const float4*)(W + (size_t)v * DIM + c);
    lo = pk2h(f.x, f.y); hi = pk2h(f.z, f.w);
  } else {
    lo = 0u; hi = 0u;
  }
  *(uint2*)(Wb + (size_t)v * DIM + c) = make_uint2(lo, hi);
}

// K3: gather Wg[b][j][:] = Wb[ids[b][j]][:]  grid (SEQ, BSZ), block 192
__global__ void k_gather(const int* __restrict__ ids, const u16* __restrict__ Wb,
                         u16* __restrict__ Wg) {
  const int b = blockIdx.y, j = blockIdx.x;
  const int row = ids[b * SEQ + j];
  const int c = threadIdx.x * 4;
  *(uint2*)(Wg + ((size_t)b * SEQ + j) * DIM + c) =
      *(const uint2*)(Wb + (size_t)row * DIM + c);
}

__global__ void k_zero(float* __restrict__ p, int n) {
  const int i = blockIdx.x * 256 + threadIdx.x;
  if (i < n) p[i] = 0.f;
}

// ---------------------------------------------------------------------------
// 128x128 2-phase core (round-3, verified) — still used by k_sims / k_hidden.
template <int LDA, int LDB>
__device__ __forceinline__ void gemm_core(const u16* __restrict__ A,
                                          const u16* __restrict__ B, int ksteps,
                                          u16* As, u16* Bs, f32x4 (&acc)[4][4],
                                          int t) {
  const int lane = t & 63, w = t >> 6, wr = w >> 1, wc = w & 1;
  const int rl = lane & 15;
  const int gsw = (((lane >> 4) ^ ((rl >> 1) & 3)) * 8);  // read granule (u16)
  const int srow = 16 * w + (lane >> 2);                  // staging row 0..63
  const int sg = (((lane & 3) ^ ((lane >> 3) & 3)) * 8);  // staged src granule
  const size_t gaBase = (size_t)srow * LDA + sg;
  const size_t gbBase = (size_t)srow * LDB + sg;
  u16* lA = As + w * 512;  // wave-uniform LDS base (+bb*4096)
  u16* lB = Bs + w * 512;

#define STAGE_(bb, kt)                                                  \
  {                                                                     \
    const u16* ga_ = A + gaBase + (size_t)(kt) * 32;                    \
    const u16* gb_ = B + gbBase + (size_t)(kt) * 32;                    \
    gload16(ga_, lA + (bb) * 4096);                                     \
    gload16(ga_ + (size_t)64 * LDA, lA + (bb) * 4096 + 2048);           \
    gload16(gb_, lB + (bb) * 4096);                                     \
    gload16(gb_ + (size_t)64 * LDB, lB + (bb) * 4096 + 2048);           \
  }

#define FRAGS_(bb)                                                      \
  half8 af[4], bf[4];                                                   \
  _Pragma("unroll") for (int m = 0; m < 4; ++m)                         \
      af[m] = *(const half8*)(As + (bb) * 4096 +                        \
                              (wr * 64 + m * 16 + rl) * 32 + gsw);      \
  _Pragma("unroll") for (int n = 0; n < 4; ++n)                         \
      bf[n] = *(const half8*)(Bs + (bb) * 4096 +                        \
                              (wc * 64 + n * 16 + rl) * 32 + gsw);      \
  _Pragma("unroll") for (int m = 0; m < 4; ++m)                         \
      _Pragma("unroll") for (int n = 0; n < 4; ++n)                     \
          acc[m][n] = __builtin_amdgcn_mfma_f32_16x16x32_f16(           \
              af[m], bf[n], acc[m][n], 0, 0, 0);

  STAGE_(0, 0);
  __syncthreads();          // drains vmcnt: buf0 ready
  int cur = 0;
  for (int kt = 0; kt < ksteps - 1; ++kt) {
    STAGE_(cur ^ 1, kt + 1);  // issue next tile early; latency hides under MFMA
    { FRAGS_(cur); }
    __syncthreads();          // drains vmcnt (staged tile) + lgkm
    cur ^= 1;
  }
  { FRAGS_(cur); }            // tail, no barrier
#undef STAGE_
#undef FRAGS_
}

// K4: sims[bk][i] += sum_j relu(content[bk] @ Wg[b]^T). grid (8,8,32)
__global__ __launch_bounds__(256) void k_sims(const u16* __restrict__ cbf,
                                              const u16* __restrict__ Wg,
                                              float* __restrict__ sims) {
  __shared__ __align__(16) u16 As[2 * 128 * 32];
  __shared__ __align__(16) u16 Bs[2 * 128 * 32];
  const int bk = blockIdx.z, b = bk >> 4;
  const int t = threadIdx.x;
  const u16* A = cbf + (size_t)bk * SEQ * DIM + (size_t)(blockIdx.y * 128) * DIM;
  const u16* B = Wg + (size_t)b * SEQ * DIM + (size_t)(blockIdx.x * 128) * DIM;
  f32x4 acc[4][4] = {};
  gemm_core<DIM, DIM>(A, B, DIM / 32, As, Bs, acc, t);
  const int lane = t & 63, w = t >> 6, wr = w >> 1;
  const int rg = lane >> 4, cl = lane & 15;
#pragma unroll
  for (int m = 0; m < 4; ++m) {
#pragma unroll
    for (int r = 0; r < 4; ++r) {
      float s = 0.f;
#pragma unroll
      for (int n = 0; n < 4; ++n) {
        const float v = acc[m][n][r];
        s += fmaxf(v, 0.f);
      }
      s += __shfl_xor(s, 1);
      s += __shfl_xor(s, 2);
      s += __shfl_xor(s, 4);
      s += __shfl_xor(s, 8);
      if (cl == 0) {
        const int i = blockIdx.y * 128 + wr * 64 + m * 16 + rg * 4 + r;
        atomicAdd(&sims[(size_t)bk * SEQ + i], s);
      }
    }
  }
}

// K5: wtsT[bk][j] = cw*score + (1-score). grid (4,32), block 256
__global__ void k_weights(const float* __restrict__ sims, const int* __restrict__ ids,
                          const float* __restrict__ cw, float* __restrict__ wtsT) {
  const int j = blockIdx.x * 256 + threadIdx.x;
  const int bk = blockIdx.y;
  const int b = bk >> 4, k = bk & 15;
  const float sm = sims[(size_t)bk * SEQ + j];
  float score = 1.f / (1.f + __expf(0.1f * sm - 6.f));  // sigmoid(-0.1*s + 6)
  score *= 1.f + (float)j * 0.01f;
  const int id = ids[b * SEQ + j];
  const float c = cw[(size_t)id * NV + k];
  wtsT[(size_t)bk * SEQ + j] = c * score + (1.f - score);
}

// K6: ctxw[bk][i][j] = f16(ctx * wtsT[bk][j]). grid 32768, block 256
__global__ void k_ctx(const float* __restrict__ ctx, const float* __restrict__ wtsT,
                      u16* __restrict__ ctxw) {
  const size_t i = ((size_t)blockIdx.x * 256 + threadIdx.x) * 4;
  const float4 c = *(const float4*)(ctx + i);
  const size_t bk = i >> 20;           // / (SEQ*SEQ)
  const int j = (int)(i & (SEQ - 1));  // column within row
  const float4 wv = *(const float4*)(wtsT + bk * SEQ + j);
  *(uint2*)(ctxw + i) =
      make_uint2(pk2h(c.x * wv.x, c.y * wv.y), pk2h(c.z * wv.z, c.w * wv.w));
}

// K7: hidden partials. grid (6, 8, 8): x=d-tile, y=i-tile, z=b*4+g
__global__ __launch_bounds__(256) void k_hidden(const u16* __restrict__ ctxw,
                                                const u16* __restrict__ cT,
                                                float* __restrict__ part) {
  __shared__ __align__(16) u16 As[2 * 128 * 32];
  __shared__ __align__(16) u16 Bs[2 * 128 * 32];
  const int z = blockIdx.z;
  const int b = z >> 2, g = z & 3;
  const int i0 = blockIdx.y * 128, d0 = blockIdx.x * 128;
  const int t = threadIdx.x;
  f32x4 acc[4][4] = {};
  for (int kk = 0; kk < 4; ++kk) {
    const int sense = g * 4 + kk;
    const u16* A = ctxw + ((size_t)(b * NV + sense) * SEQ + i0) * SEQ;
    const u16* B = cT + ((size_t)(b * NV + sense) * DIM + d0) * SEQ;
    gemm_core<SEQ, SEQ>(A, B, SEQ / 32, As, Bs, acc, t);
    __syncthreads();  // tail reads done before next call restages buf0
  }
  const int lane = t & 63, w = t >> 6, wr = w >> 1, wc = w & 1;
  const int rg = lane >> 4, cl = lane & 15;
  float* P = part + ((size_t)(g * BSZ + b) * SEQ + i0) * DIM + d0;
#pragma unroll
  for (int m = 0; m < 4; ++m)
#pragma unroll
    for (int n = 0; n < 4; ++n)
#pragma unroll
      for (int r = 0; r < 4; ++r)
        P[(size_t)(wr * 64 + m * 16 + rg * 4 + r) * DIM + wc * 64 + n * 16 + cl] =
            acc[m][n][r];
}

// K8: hid = f16(sum_g part[g]). grid 1536, block 256
__global__ void k_reduce(const float* __restrict__ part, u16* __restrict__ hid) {
  const size_t i = ((size_t)blockIdx.x * 256 + threadIdx.x) * 4;
  const size_t NHID = (size_t)BSZ * SEQ * DIM;
  float4 s = {0.f, 0.f, 0.f, 0.f};
#pragma unroll
  for (int g = 0; g < 4; ++g) {
    const float4 p = *(const float4*)(part + (size_t)g * NHID + i);
    s.x += p.x; s.y += p.y; s.z += p.z; s.w += p.w;
  }
  *(uint2*)(hid + i) = make_uint2(pk2h(s.x, s.y), pk2h(s.z, s.w));
}

// ---------------------------------------------------------------------------
// K9: logits = hid @ Wb^T.  256x256 tile, BK=32, 512 thr (8 waves, 2M x 4N),
// 4-deep LDS ring (128 KiB), counted vmcnt(8): tile t+3 staged during tile t
// into a buffer whose reads finished at the t-1 boundary barrier (provably
// idle), so boundary waits never drain to 0 mid-loop (T3+T4). Granule swizzle
// slot = g ^ ((row>>1)&3) on BOTH staged source and frag read (rule #21).
// Grid: 1576 = 8 i-tiles x 197 v-tiles (last v-tile clamped: overlap rows are
// recomputed identically — benign). XCD-swizzled (1576 % 8 == 0).
__global__ __launch_bounds__(512) void k_logits(const u16* __restrict__ hid,
                                                const u16* __restrict__ Wb,
                                                float* __restrict__ out) {
  __shared__ __align__(16) u16 lds[65536];  // 4 x (A 8192 + B 8192) u16
  const int bid = blockIdx.x;
  const int swz = (bid & 7) * 197 + (bid >> 3);
  const int vt = swz >> 3, it = swz & 7;
  const int i0 = it * 256;
  const int v0 = (vt == 196) ? (VOCP - 256) : vt * 256;
  const int t = threadIdx.x;
  const int lane = t & 63, w = t >> 6;
  const int wm = w >> 2, wn = w & 3;
  const int rl = lane & 15, kg = lane >> 4;
  const int gsw = ((kg ^ ((rl >> 1) & 3))) * 8;    // frag read granule (u16)
  const int aoff = (wm * 128 + rl) * 32 + gsw;     // af m: + m*512
  const int boff = 8192 + (wn * 64 + rl) * 32 + gsw;  // bf n: + n*512
  // staging: unit = 128 rows x 4 slots; thread -> (row = t>>2, slot = t&3)
  const int srow = t >> 2;
  const int sgg = ((t & 3) ^ ((t >> 3) & 3)) * 8;  // pre-swizzled src granule
  const u16* gA0 = hid + (size_t)(i0 + srow) * DIM + sgg;
  const u16* gA1 = hid + (size_t)(i0 + 128 + srow) * DIM + sgg;
  const u16* gB0 = Wb + (size_t)(v0 + srow) * DIM + sgg;
  const u16* gB1 = Wb + (size_t)(v0 + 128 + srow) * DIM + sgg;
  const int wb = w * 512;  // wave-uniform LDS sub-base

#define STG_A(tt)                                              \
  {                                                            \
    u16* d_ = lds + ((tt) & 3) * 16384 + wb;                   \
    gload16(gA0 + (size_t)(tt) * 32, d_);                      \
    gload16(gA1 + (size_t)(tt) * 32, d_ + 4096);               \
  }
#define STG_B(tt)                                              \
  {                                                            \
    u16* d_ = lds + ((tt) & 3) * 16384 + 8192 + wb;            \
    gload16(gB0 + (size_t)(tt) * 32, d_);                      \
    gload16(gB1 + (size_t)(tt) * 32, d_ + 4096);               \
  }

  f32x4 acc[8][4] = {};
  STG_A(0); STG_B(0); STG_A(1); STG_B(1); STG_A(2); STG_B(2);
  for (int tt = 0; tt < 24; ++tt) {
    if (tt < 22)
      asm volatile("s_waitcnt vmcnt(8)" ::: "memory");
    else if (tt == 22)
      asm volatile("s_waitcnt vmcnt(4)" ::: "memory");
    else
      asm volatile("s_waitcnt vmcnt(0)" ::: "memory");
    __builtin_amdgcn_s_barrier();      // all waves' tile-tt loads landed
    __builtin_amdgcn_sched_barrier(0);
    const u16* bp = lds + (tt & 3) * 16384;
    half8 af[4], bf[4];
#pragma unroll
    for (int n = 0; n < 4; ++n) bf[n] = *(const half8*)(bp + boff + n * 512);
#pragma unroll
    for (int m = 0; m < 4; ++m) af[m] = *(const half8*)(bp + aoff + m * 512);
    if (tt + 3 < 24) STG_A(tt + 3);
    __builtin_amdgcn_s_setprio(1);
#pragma unroll
    for (int m = 0; m < 4; ++m)
#pragma unroll
      for (int n = 0; n < 4; ++n)
        acc[m][n] =
            __builtin_amdgcn_mfma_f32_16x16x32_f16(af[m], bf[n], acc[m][n], 0, 0, 0);
    __builtin_amdgcn_s_setprio(0);
    __builtin_amdgcn_s_barrier();      // phase boundary (lockstep)
#pragma unroll
    for (int m = 0; m < 4; ++m)
      af[m] = *(const half8*)(bp + aoff + 2048 + m * 512);
    if (tt + 3 < 24) STG_B(tt + 3);
    __builtin_amdgcn_s_setprio(1);
#pragma unroll
    for (int m = 0; m < 4; ++m)
#pragma unroll
      for (int n = 0; n < 4; ++n)
        acc[4 + m][n] =
            __builtin_amdgcn_mfma_f32_16x16x32_f16(af[m], bf[n], acc[4 + m][n], 0, 0, 0);
    __builtin_amdgcn_s_setprio(0);
  }
#undef STG_A
#undef STG_B
  // epilogue: C/D layout col=lane&15 (v), row=(lane>>4)*4+r (i); NT stores
#pragma unroll
  for (int m = 0; m < 8; ++m)
#pragma unroll
    for (int n = 0; n < 4; ++n) {
      const int v = v0 + wn * 64 + n * 16 + rl;
      if (v < VOC) {
        const int ib = i0 + wm * 128 + m * 16 + kg * 4;
#pragma unroll
        for (int r = 0; r < 4; ++r)
          __builtin_nontemporal_store(acc[m][n][r],
                                      &out[(size_t)(ib + r) * VOC + v]);
      }
    }
}

// ---------------------------------------------------------------------------
extern "C" void kernel_launch(void* const* d_in, const int* in_sizes, int n_in,
                              void* d_out, int out_size, void* d_ws, size_t ws_size,
                              hipStream_t stream) {
  const int* ids = (const int*)d_in[0];
  const float* content = (const float*)d_in[1];
  const float* ctx = (const float*)d_in[2];
  const float* W = (const float*)d_in[3];
  const float* cw = (const float*)d_in[4];
  float* out = (float*)d_out;
  char* ws = (char*)d_ws;

  // workspace layout (bytes, all 256-aligned); total 248,446,976
  u16* cbf  = (u16*)(ws);                  // 50,331,648  [32][S][D] f16
  u16* cT   = (u16*)(ws + 50331648);       // 50,331,648  [32][D][S] f16
  u16* Wb   = (u16*)(ws + 100663296);      // 77,266,944  [VOCP][D] f16
  u16* Wg   = (u16*)(ws + 177930240);      //  3,145,728  [B][S][D] f16
  u16* ctxw = (u16*)(ws + 181075968);      // 67,108,864  [32][S][S] f16
  float* sims = (float*)(ws + 248184832);  //    131,072  [32][S] f32
  float* wtsT = (float*)(ws + 248315904);  //    131,072  [32][S] f32
  // aliases (safe by dataflow: source buffer dead before alias first written)
  float* part = (float*)cbf;               // 25,165,824  [4][B][S][D] f32
  u16* hid = Wg;                           //  3,145,728  [B*S][D] f16

  k_prep_content<<<dim3(DIM / 32, SEQ / 32, BSZ * NV), dim3(32, 8), 0, stream>>>(
      content, cbf, cT);
  k_prep_w<<<VOCP, 192, 0, stream>>>(W, Wb);
  k_gather<<<dim3(SEQ, BSZ), 192, 0, stream>>>(ids, Wb, Wg);
  k_zero<<<128, 256, 0, stream>>>(sims, BSZ * NV * SEQ);
  k_sims<<<dim3(8, 8, BSZ * NV), 256, 0, stream>>>(cbf, Wg, sims);
  k_weights<<<dim3(4, BSZ * NV), 256, 0, stream>>>(sims, ids, cw, wtsT);
  k_ctx<<<32768, 256, 0, stream>>>(ctx, wtsT, ctxw);
  k_hidden<<<dim3(6, 8, 8), 256, 0, stream>>>(ctxw, cT, part);
  k_reduce<<<1536, 256, 0, stream>>>(part, hid);
  k_logits<<<8 * 197, 512, 0, stream>>>(hid, Wb, out);
}

// Round 5
// 639.248 us; speedup vs baseline: 1.2442x; 1.2442x over previous
//
#include <hip/hip_runtime.h>
#include <cstdint>
#include <cstddef>

#define BSZ 2
#define NV 16
#define SEQ 1024
#define DIM 768
#define VOC 50257
#define VOCP 50304   // padded to multiple of 128

typedef unsigned int u32;
typedef unsigned short u16;
typedef _Float16 half8 __attribute__((ext_vector_type(8)));
typedef float f32x4 __attribute__((ext_vector_type(4)));

__device__ __forceinline__ u16 f2h(float f) {
  return __builtin_bit_cast(unsigned short, (_Float16)f);
}
__device__ __forceinline__ u32 pk2h(float a, float b) {
  return (u32)f2h(a) | ((u32)f2h(b) << 16);
}

// async global->LDS, 16B per lane; LDS dest = wave-uniform base + lane*16
__device__ __forceinline__ void gload16(const u16* g, u16* l) {
  __builtin_amdgcn_global_load_lds(
      (const __attribute__((address_space(1))) void*)g,
      (__attribute__((address_space(3))) void*)l, 16, 0, 0);
}

// ---------------------------------------------------------------------------
// K1: content f32 -> f16 (normal + transposed per (b,k) slice)
__global__ void k_prep_content(const float* __restrict__ content,
                               u16* __restrict__ cbf, u16* __restrict__ cT) {
  __shared__ u16 tile[32][33];
  const int bk = blockIdx.z;
  const int d0 = blockIdx.x * 32, j0 = blockIdx.y * 32;
  const float* src = content + (size_t)bk * SEQ * DIM;
  u16* dst = cbf + (size_t)bk * SEQ * DIM;
  u16* dstT = cT + (size_t)bk * DIM * SEQ;
  const int c = threadIdx.x;
#pragma unroll
  for (int rr = 0; rr < 4; ++rr) {
    const int r = threadIdx.y * 4 + rr;
    const float v = src[(size_t)(j0 + r) * DIM + d0 + c];
    const u16 bv = f2h(v);
    dst[(size_t)(j0 + r) * DIM + d0 + c] = bv;
    tile[r][c] = bv;
  }
  __syncthreads();
#pragma unroll
  for (int rr = 0; rr < 4; ++rr) {
    const int r = threadIdx.y * 4 + rr;       // d-local
    dstT[(size_t)(d0 + r) * SEQ + j0 + c] = tile[c][r];
  }
}

// K2: lm_head_weight f32 -> f16, padded rows zeroed. grid VOCP, block 192
__global__ void k_prep_w(const float* __restrict__ W, u16* __restrict__ Wb) {
  const int v = blockIdx.x;
  const int c = threadIdx.x * 4;
  u32 lo, hi;
  if (v < VOC) {
    const float4 f = *(const float4*)(W + (size_t)v * DIM + c);
    lo = pk2h(f.x, f.y); hi = pk2h(f.z, f.w);
  } else {
    lo = 0u; hi = 0u;
  }
  *(uint2*)(Wb + (size_t)v * DIM + c) = make_uint2(lo, hi);
}

// K3: gather Wg[b][j][:] = Wb[ids[b][j]][:]  grid (SEQ, BSZ), block 192
__global__ void k_gather(const int* __restrict__ ids, const u16* __restrict__ Wb,
                         u16* __restrict__ Wg) {
  const int b = blockIdx.y, j = blockIdx.x;
  const int row = ids[b * SEQ + j];
  const int c = threadIdx.x * 4;
  *(uint2*)(Wg + ((size_t)b * SEQ + j) * DIM + c) =
      *(const uint2*)(Wb + (size_t)row * DIM + c);
}

__global__ void k_zero(float* __restrict__ p, int n) {
  const int i = blockIdx.x * 256 + threadIdx.x;
  if (i < n) p[i] = 0.f;
}

// ---------------------------------------------------------------------------
// 128x128 2-phase core (round-3, verified) — used by k_hidden.
// Double-buffered: STAGE(next) issued before FRAGS(cur); __syncthreads drains.
// Granule swizzle (16B units): slot = g ^ ((row>>1)&3) applied on BOTH the
// staged global source and the fragment read (involution, rule #21) -> 0
// LDS bank conflicts (verified round 3).
template <int LDA, int LDB>
__device__ __forceinline__ void gemm_core(const u16* __restrict__ A,
                                          const u16* __restrict__ B, int ksteps,
                                          u16* As, u16* Bs, f32x4 (&acc)[4][4],
                                          int t) {
  const int lane = t & 63, w = t >> 6, wr = w >> 1, wc = w & 1;
  const int rl = lane & 15;
  const int gsw = (((lane >> 4) ^ ((rl >> 1) & 3)) * 8);  // read granule (u16)
  const int srow = 16 * w + (lane >> 2);                  // staging row 0..63
  const int sg = (((lane & 3) ^ ((lane >> 3) & 3)) * 8);  // staged src granule
  const size_t gaBase = (size_t)srow * LDA + sg;
  const size_t gbBase = (size_t)srow * LDB + sg;
  u16* lA = As + w * 512;  // wave-uniform LDS base (+bb*4096)
  u16* lB = Bs + w * 512;

#define STAGE_(bb, kt)                                                  \
  {                                                                     \
    const u16* ga_ = A + gaBase + (size_t)(kt) * 32;                    \
    const u16* gb_ = B + gbBase + (size_t)(kt) * 32;                    \
    gload16(ga_, lA + (bb) * 4096);                                     \
    gload16(ga_ + (size_t)64 * LDA, lA + (bb) * 4096 + 2048);           \
    gload16(gb_, lB + (bb) * 4096);                                     \
    gload16(gb_ + (size_t)64 * LDB, lB + (bb) * 4096 + 2048);           \
  }

#define FRAGS_(bb)                                                      \
  half8 af[4], bf[4];                                                   \
  _Pragma("unroll") for (int m = 0; m < 4; ++m)                         \
      af[m] = *(const half8*)(As + (bb) * 4096 +                        \
                              (wr * 64 + m * 16 + rl) * 32 + gsw);      \
  _Pragma("unroll") for (int n = 0; n < 4; ++n)                         \
      bf[n] = *(const half8*)(Bs + (bb) * 4096 +                        \
                              (wc * 64 + n * 16 + rl) * 32 + gsw);      \
  _Pragma("unroll") for (int m = 0; m < 4; ++m)                         \
      _Pragma("unroll") for (int n = 0; n < 4; ++n)                     \
          acc[m][n] = __builtin_amdgcn_mfma_f32_16x16x32_f16(           \
              af[m], bf[n], acc[m][n], 0, 0, 0);

  STAGE_(0, 0);
  __syncthreads();          // buf0 ready
  int cur = 0;
  for (int kt = 0; kt < ksteps - 1; ++kt) {
    STAGE_(cur ^ 1, kt + 1);  // issue next tile early
    { FRAGS_(cur); }
    __syncthreads();
    cur ^= 1;
  }
  { FRAGS_(cur); }            // tail, no barrier
#undef STAGE_
#undef FRAGS_
}

// ---------------------------------------------------------------------------
// Dual-A 2-phase core: one block = 256(i) x 128(v/j), two A tiles share one
// staged B tile. Per K-step: 6 gloads + 12 ds_read_b128 + 32 MFMA (vs
// 4/8/16 single) -> higher MFMA:VALU issue ratio, barriers amortized 2x.
// Same sync + swizzle discipline as gemm_core.
template <int LDA, int LDB>
__device__ __forceinline__ void gemm_core2(const u16* __restrict__ A0,
                                           const u16* __restrict__ A1,
                                           const u16* __restrict__ B, int ksteps,
                                           u16* As0, u16* As1, u16* Bs,
                                           f32x4 (&acc0)[4][4],
                                           f32x4 (&acc1)[4][4], int t) {
  const int lane = t & 63, w = t >> 6, wr = w >> 1, wc = w & 1;
  const int rl = lane & 15;
  const int gsw = (((lane >> 4) ^ ((rl >> 1) & 3)) * 8);
  const int srow = 16 * w + (lane >> 2);
  const int sg = (((lane & 3) ^ ((lane >> 3) & 3)) * 8);
  const size_t gaBase = (size_t)srow * LDA + sg;
  const size_t gbBase = (size_t)srow * LDB + sg;
  u16* lA0 = As0 + w * 512;
  u16* lA1 = As1 + w * 512;
  u16* lB = Bs + w * 512;

#define STAGE2_(bb, kt)                                                 \
  {                                                                     \
    const u16* ga0_ = A0 + gaBase + (size_t)(kt) * 32;                  \
    const u16* ga1_ = A1 + gaBase + (size_t)(kt) * 32;                  \
    const u16* gb_ = B + gbBase + (size_t)(kt) * 32;                    \
    gload16(ga0_, lA0 + (bb) * 4096);                                   \
    gload16(ga0_ + (size_t)64 * LDA, lA0 + (bb) * 4096 + 2048);         \
    gload16(ga1_, lA1 + (bb) * 4096);                                   \
    gload16(ga1_ + (size_t)64 * LDA, lA1 + (bb) * 4096 + 2048);         \
    gload16(gb_, lB + (bb) * 4096);                                     \
    gload16(gb_ + (size_t)64 * LDB, lB + (bb) * 4096 + 2048);           \
  }

#define FRAGS2_(bb)                                                     \
  half8 af0[4], af1[4], bf[4];                                          \
  _Pragma("unroll") for (int n = 0; n < 4; ++n)                         \
      bf[n] = *(const half8*)(Bs + (bb) * 4096 +                        \
                              (wc * 64 + n * 16 + rl) * 32 + gsw);      \
  _Pragma("unroll") for (int m = 0; m < 4; ++m)                         \
      af0[m] = *(const half8*)(As0 + (bb) * 4096 +                      \
                               (wr * 64 + m * 16 + rl) * 32 + gsw);     \
  _Pragma("unroll") for (int m = 0; m < 4; ++m)                         \
      af1[m] = *(const half8*)(As1 + (bb) * 4096 +                      \
                               (wr * 64 + m * 16 + rl) * 32 + gsw);     \
  _Pragma("unroll") for (int m = 0; m < 4; ++m)                         \
      _Pragma("unroll") for (int n = 0; n < 4; ++n)                     \
          acc0[m][n] = __builtin_amdgcn_mfma_f32_16x16x32_f16(          \
              af0[m], bf[n], acc0[m][n], 0, 0, 0);                      \
  _Pragma("unroll") for (int m = 0; m < 4; ++m)                         \
      _Pragma("unroll") for (int n = 0; n < 4; ++n)                     \
          acc1[m][n] = __builtin_amdgcn_mfma_f32_16x16x32_f16(          \
              af1[m], bf[n], acc1[m][n], 0, 0, 0);

  STAGE2_(0, 0);
  __syncthreads();
  int cur = 0;
  for (int kt = 0; kt < ksteps - 1; ++kt) {
    STAGE2_(cur ^ 1, kt + 1);
    { FRAGS2_(cur); }
    __syncthreads();
    cur ^= 1;
  }
  { FRAGS2_(cur); }
#undef STAGE2_
#undef FRAGS2_
}

// K4: sims[bk][i] += sum_j relu(content[bk] @ Wg[b]^T). grid (8,4,32):
// x = j-tile (8), y = i-pair (4: 256 rows/block), z = bk. Dual-A core.
__global__ __launch_bounds__(256, 2) void k_sims(const u16* __restrict__ cbf,
                                                 const u16* __restrict__ Wg,
                                                 float* __restrict__ sims) {
  __shared__ __align__(16) u16 As0[2 * 128 * 32];
  __shared__ __align__(16) u16 As1[2 * 128 * 32];
  __shared__ __align__(16) u16 Bs[2 * 128 * 32];
  const int bk = blockIdx.z, b = bk >> 4;
  const int t = threadIdx.x;
  const int i0 = blockIdx.y * 256;
  const u16* A0 = cbf + (size_t)bk * SEQ * DIM + (size_t)i0 * DIM;
  const u16* A1 = A0 + (size_t)128 * DIM;
  const u16* B = Wg + (size_t)b * SEQ * DIM + (size_t)(blockIdx.x * 128) * DIM;
  f32x4 acc0[4][4] = {}, acc1[4][4] = {};
  gemm_core2<DIM, DIM>(A0, A1, B, DIM / 32, As0, As1, Bs, acc0, acc1, t);
  const int lane = t & 63, w = t >> 6, wr = w >> 1;
  const int rg = lane >> 4, cl = lane & 15;
#pragma unroll
  for (int m = 0; m < 4; ++m) {
#pragma unroll
    for (int r = 0; r < 4; ++r) {
      float s0 = 0.f, s1 = 0.f;
#pragma unroll
      for (int n = 0; n < 4; ++n) {
        s0 += fmaxf(acc0[m][n][r], 0.f);
        s1 += fmaxf(acc1[m][n][r], 0.f);
      }
      s0 += __shfl_xor(s0, 1); s1 += __shfl_xor(s1, 1);
      s0 += __shfl_xor(s0, 2); s1 += __shfl_xor(s1, 2);
      s0 += __shfl_xor(s0, 4); s1 += __shfl_xor(s1, 4);
      s0 += __shfl_xor(s0, 8); s1 += __shfl_xor(s1, 8);
      if (cl == 0) {
        const int i = i0 + wr * 64 + m * 16 + rg * 4 + r;
        atomicAdd(&sims[(size_t)bk * SEQ + i], s0);
        atomicAdd(&sims[(size_t)bk * SEQ + i + 128], s1);
      }
    }
  }
}

// K5: wtsT[bk][j] = cw*score + (1-score). grid (4,32), block 256
__global__ void k_weights(const float* __restrict__ sims, const int* __restrict__ ids,
                          const float* __restrict__ cw, float* __restrict__ wtsT) {
  const int j = blockIdx.x * 256 + threadIdx.x;
  const int bk = blockIdx.y;
  const int b = bk >> 4, k = bk & 15;
  const float sm = sims[(size_t)bk * SEQ + j];
  float score = 1.f / (1.f + __expf(0.1f * sm - 6.f));  // sigmoid(-0.1*s + 6)
  score *= 1.f + (float)j * 0.01f;
  const int id = ids[b * SEQ + j];
  const float c = cw[(size_t)id * NV + k];
  wtsT[(size_t)bk * SEQ + j] = c * score + (1.f - score);
}

// K6: ctxw[bk][i][j] = f16(ctx * wtsT[bk][j]). grid 32768, block 256
__global__ void k_ctx(const float* __restrict__ ctx, const float* __restrict__ wtsT,
                      u16* __restrict__ ctxw) {
  const size_t i = ((size_t)blockIdx.x * 256 + threadIdx.x) * 4;
  const float4 c = *(const float4*)(ctx + i);
  const size_t bk = i >> 20;           // / (SEQ*SEQ)
  const int j = (int)(i & (SEQ - 1));  // column within row
  const float4 wv = *(const float4*)(wtsT + bk * SEQ + j);
  *(uint2*)(ctxw + i) =
      make_uint2(pk2h(c.x * wv.x, c.y * wv.y), pk2h(c.z * wv.z, c.w * wv.w));
}

// K7: hidden partials. grid (6, 8, 8): x=d-tile, y=i-tile, z=b*4+g
__global__ __launch_bounds__(256) void k_hidden(const u16* __restrict__ ctxw,
                                                const u16* __restrict__ cT,
                                                float* __restrict__ part) {
  __shared__ __align__(16) u16 As[2 * 128 * 32];
  __shared__ __align__(16) u16 Bs[2 * 128 * 32];
  const int z = blockIdx.z;
  const int b = z >> 2, g = z & 3;
  const int i0 = blockIdx.y * 128, d0 = blockIdx.x * 128;
  const int t = threadIdx.x;
  f32x4 acc[4][4] = {};
  for (int kk = 0; kk < 4; ++kk) {
    const int sense = g * 4 + kk;
    const u16* A = ctxw + ((size_t)(b * NV + sense) * SEQ + i0) * SEQ;
    const u16* B = cT + ((size_t)(b * NV + sense) * DIM + d0) * SEQ;
    gemm_core<SEQ, SEQ>(A, B, SEQ / 32, As, Bs, acc, t);
    __syncthreads();  // tail reads done before next call restages buf0
  }
  const int lane = t & 63, w = t >> 6, wr = w >> 1, wc = w & 1;
  const int rg = lane >> 4, cl = lane & 15;
  float* P = part + ((size_t)(g * BSZ + b) * SEQ + i0) * DIM + d0;
#pragma unroll
  for (int m = 0; m < 4; ++m)
#pragma unroll
    for (int n = 0; n < 4; ++n)
#pragma unroll
      for (int r = 0; r < 4; ++r)
        P[(size_t)(wr * 64 + m * 16 + rg * 4 + r) * DIM + wc * 64 + n * 16 + cl] =
            acc[m][n][r];
}

// K8: hid = f16(sum_g part[g]). grid 1536, block 256
__global__ void k_reduce(const float* __restrict__ part, u16* __restrict__ hid) {
  const size_t i = ((size_t)blockIdx.x * 256 + threadIdx.x) * 4;
  const size_t NHID = (size_t)BSZ * SEQ * DIM;
  float4 s = {0.f, 0.f, 0.f, 0.f};
#pragma unroll
  for (int g = 0; g < 4; ++g) {
    const float4 p = *(const float4*)(part + (size_t)g * NHID + i);
    s.x += p.x; s.y += p.y; s.z += p.z; s.w += p.w;
  }
  *(uint2*)(hid + i) = make_uint2(pk2h(s.x, s.y), pk2h(s.z, s.w));
}

// K9: logits = hid @ Wb^T. Dual-A: block = 256(i) x 128(v). Grid 3144 =
// 8 i-pairs x 393 v-tiles (VOCP = 393*128 exactly), XCD-swizzled
// (3144 % 8 == 0). Plain stores (NT caused 2x write amplification: row
// stride 201028 B is not 64B-aligned; L2 merging needs to stay on).
__global__ __launch_bounds__(256, 2) void k_logits(const u16* __restrict__ hid,
                                                   const u16* __restrict__ Wb,
                                                   float* __restrict__ out) {
  __shared__ __align__(16) u16 As0[2 * 128 * 32];
  __shared__ __align__(16) u16 As1[2 * 128 * 32];
  __shared__ __align__(16) u16 Bs[2 * 128 * 32];
  const int bid = blockIdx.x;
  const int swz = (bid & 7) * 393 + (bid >> 3);
  const int it = swz & 7, vt = swz >> 3;
  const int i0 = it * 256, v0 = vt * 128;
  const int t = threadIdx.x;
  const u16* A0 = hid + (size_t)i0 * DIM;
  const u16* A1 = A0 + (size_t)128 * DIM;
  const u16* B = Wb + (size_t)v0 * DIM;
  f32x4 acc0[4][4] = {}, acc1[4][4] = {};
  gemm_core2<DIM, DIM>(A0, A1, B, DIM / 32, As0, As1, Bs, acc0, acc1, t);
  const int lane = t & 63, w = t >> 6, wr = w >> 1, wc = w & 1;
  const int rg = lane >> 4, cl = lane & 15;
#pragma unroll
  for (int m = 0; m < 4; ++m)
#pragma unroll
    for (int n = 0; n < 4; ++n) {
      const int vv = v0 + wc * 64 + n * 16 + cl;
      if (vv < VOC) {
        const int i = i0 + wr * 64 + m * 16 + rg * 4;
#pragma unroll
        for (int r = 0; r < 4; ++r)
          out[(size_t)(i + r) * VOC + vv] = acc0[m][n][r];
#pragma unroll
        for (int r = 0; r < 4; ++r)
          out[(size_t)(i + 128 + r) * VOC + vv] = acc1[m][n][r];
      }
    }
}

// ---------------------------------------------------------------------------
extern "C" void kernel_launch(void* const* d_in, const int* in_sizes, int n_in,
                              void* d_out, int out_size, void* d_ws, size_t ws_size,
                              hipStream_t stream) {
  const int* ids = (const int*)d_in[0];
  const float* content = (const float*)d_in[1];
  const float* ctx = (const float*)d_in[2];
  const float* W = (const float*)d_in[3];
  const float* cw = (const float*)d_in[4];
  float* out = (float*)d_out;
  char* ws = (char*)d_ws;

  // workspace layout (bytes, all 256-aligned); total 248,446,976
  u16* cbf  = (u16*)(ws);                  // 50,331,648  [32][S][D] f16
  u16* cT   = (u16*)(ws + 50331648);       // 50,331,648  [32][D][S] f16
  u16* Wb   = (u16*)(ws + 100663296);      // 77,266,944  [VOCP][D] f16
  u16* Wg   = (u16*)(ws + 177930240);      //  3,145,728  [B][S][D] f16
  u16* ctxw = (u16*)(ws + 181075968);      // 67,108,864  [32][S][S] f16
  float* sims = (float*)(ws + 248184832);  //    131,072  [32][S] f32
  float* wtsT = (float*)(ws + 248315904);  //    131,072  [32][S] f32
  // aliases (safe by dataflow: source buffer dead before alias first written)
  float* part = (float*)cbf;               // 25,165,824  [4][B][S][D] f32
  u16* hid = Wg;                           //  3,145,728  [B*S][D] f16

  k_prep_content<<<dim3(DIM / 32, SEQ / 32, BSZ * NV), dim3(32, 8), 0, stream>>>(
      content, cbf, cT);
  k_prep_w<<<VOCP, 192, 0, stream>>>(W, Wb);
  k_gather<<<dim3(SEQ, BSZ), 192, 0, stream>>>(ids, Wb, Wg);
  k_zero<<<128, 256, 0, stream>>>(sims, BSZ * NV * SEQ);
  k_sims<<<dim3(8, 4, BSZ * NV), 256, 0, stream>>>(cbf, Wg, sims);
  k_weights<<<dim3(4, BSZ * NV), 256, 0, stream>>>(sims, ids, cw, wtsT);
  k_ctx<<<32768, 256, 0, stream>>>(ctx, wtsT, ctxw);
  k_hidden<<<dim3(6, 8, 8), 256, 0, stream>>>(ctxw, cT, part);
  k_reduce<<<1536, 256, 0, stream>>>(part, hid);
  k_logits<<<8 * 393, 256, 0, stream>>>(hid, Wb, out);
}

// Round 6
// 591.445 us; speedup vs baseline: 1.3447x; 1.0808x over previous
//
#include <hip/hip_runtime.h>
#include <cstdint>
#include <cstddef>

#define BSZ 2
#define NV 16
#define SEQ 1024
#define DIM 768
#define VOC 50257
#define VOCP 50304   // padded to multiple of 128

typedef unsigned int u32;
typedef unsigned short u16;
typedef _Float16 half8 __attribute__((ext_vector_type(8)));
typedef float f32x4 __attribute__((ext_vector_type(4)));

__device__ __forceinline__ u16 f2h(float f) {
  return __builtin_bit_cast(unsigned short, (_Float16)f);
}
__device__ __forceinline__ u32 pk2h(float a, float b) {
  return (u32)f2h(a) | ((u32)f2h(b) << 16);
}

// async global->LDS, 16B per lane; LDS dest = wave-uniform base + lane*16
__device__ __forceinline__ void gload16(const u16* g, u16* l) {
  __builtin_amdgcn_global_load_lds(
      (const __attribute__((address_space(1))) void*)g,
      (__attribute__((address_space(3))) void*)l, 16, 0, 0);
}

// ---------------------------------------------------------------------------
// K1: content f32 -> f16 (normal + transposed per (b,k) slice)
__global__ void k_prep_content(const float* __restrict__ content,
                               u16* __restrict__ cbf, u16* __restrict__ cT) {
  __shared__ u16 tile[32][33];
  const int bk = blockIdx.z;
  const int d0 = blockIdx.x * 32, j0 = blockIdx.y * 32;
  const float* src = content + (size_t)bk * SEQ * DIM;
  u16* dst = cbf + (size_t)bk * SEQ * DIM;
  u16* dstT = cT + (size_t)bk * DIM * SEQ;
  const int c = threadIdx.x;
#pragma unroll
  for (int rr = 0; rr < 4; ++rr) {
    const int r = threadIdx.y * 4 + rr;
    const float v = src[(size_t)(j0 + r) * DIM + d0 + c];
    const u16 bv = f2h(v);
    dst[(size_t)(j0 + r) * DIM + d0 + c] = bv;
    tile[r][c] = bv;
  }
  __syncthreads();
#pragma unroll
  for (int rr = 0; rr < 4; ++rr) {
    const int r = threadIdx.y * 4 + rr;       // d-local
    dstT[(size_t)(d0 + r) * SEQ + j0 + c] = tile[c][r];
  }
}

// K2: lm_head_weight f32 -> f16, padded rows zeroed. grid VOCP, block 192
__global__ void k_prep_w(const float* __restrict__ W, u16* __restrict__ Wb) {
  const int v = blockIdx.x;
  const int c = threadIdx.x * 4;
  u32 lo, hi;
  if (v < VOC) {
    const float4 f = *(const float4*)(W + (size_t)v * DIM + c);
    lo = pk2h(f.x, f.y); hi = pk2h(f.z, f.w);
  } else {
    lo = 0u; hi = 0u;
  }
  *(uint2*)(Wb + (size_t)v * DIM + c) = make_uint2(lo, hi);
}

// K3: gather Wg[b][j][:] = Wb[ids[b][j]][:]  grid (SEQ, BSZ), block 192
__global__ void k_gather(const int* __restrict__ ids, const u16* __restrict__ Wb,
                         u16* __restrict__ Wg) {
  const int b = blockIdx.y, j = blockIdx.x;
  const int row = ids[b * SEQ + j];
  const int c = threadIdx.x * 4;
  *(uint2*)(Wg + ((size_t)b * SEQ + j) * DIM + c) =
      *(const uint2*)(Wb + (size_t)row * DIM + c);
}

__global__ void k_zero(float* __restrict__ p, int n) {
  const int i = blockIdx.x * 256 + threadIdx.x;
  if (i < n) p[i] = 0.f;
}

// ---------------------------------------------------------------------------
// 128x128 2-phase core (round-3, verified) — used by k_hidden.
template <int LDA, int LDB>
__device__ __forceinline__ void gemm_core(const u16* __restrict__ A,
                                          const u16* __restrict__ B, int ksteps,
                                          u16* As, u16* Bs, f32x4 (&acc)[4][4],
                                          int t) {
  const int lane = t & 63, w = t >> 6, wr = w >> 1, wc = w & 1;
  const int rl = lane & 15;
  const int gsw = (((lane >> 4) ^ ((rl >> 1) & 3)) * 8);  // read granule (u16)
  const int srow = 16 * w + (lane >> 2);                  // staging row 0..63
  const int sg = (((lane & 3) ^ ((lane >> 3) & 3)) * 8);  // staged src granule
  const size_t gaBase = (size_t)srow * LDA + sg;
  const size_t gbBase = (size_t)srow * LDB + sg;
  u16* lA = As + w * 512;  // wave-uniform LDS base (+bb*4096)
  u16* lB = Bs + w * 512;

#define STAGE_(bb, kt)                                                  \
  {                                                                     \
    const u16* ga_ = A + gaBase + (size_t)(kt) * 32;                    \
    const u16* gb_ = B + gbBase + (size_t)(kt) * 32;                    \
    gload16(ga_, lA + (bb) * 4096);                                     \
    gload16(ga_ + (size_t)64 * LDA, lA + (bb) * 4096 + 2048);           \
    gload16(gb_, lB + (bb) * 4096);                                     \
    gload16(gb_ + (size_t)64 * LDB, lB + (bb) * 4096 + 2048);           \
  }

#define FRAGS_(bb)                                                      \
  half8 af[4], bf[4];                                                   \
  _Pragma("unroll") for (int m = 0; m < 4; ++m)                         \
      af[m] = *(const half8*)(As + (bb) * 4096 +                        \
                              (wr * 64 + m * 16 + rl) * 32 + gsw);      \
  _Pragma("unroll") for (int n = 0; n < 4; ++n)                         \
      bf[n] = *(const half8*)(Bs + (bb) * 4096 +                        \
                              (wc * 64 + n * 16 + rl) * 32 + gsw);      \
  _Pragma("unroll") for (int m = 0; m < 4; ++m)                         \
      _Pragma("unroll") for (int n = 0; n < 4; ++n)                     \
          acc[m][n] = __builtin_amdgcn_mfma_f32_16x16x32_f16(           \
              af[m], bf[n], acc[m][n], 0, 0, 0);

  STAGE_(0, 0);
  __syncthreads();          // buf0 ready
  int cur = 0;
  for (int kt = 0; kt < ksteps - 1; ++kt) {
    STAGE_(cur ^ 1, kt + 1);  // issue next tile early
    { FRAGS_(cur); }
    __syncthreads();
    cur ^= 1;
  }
  { FRAGS_(cur); }            // tail, no barrier
#undef STAGE_
#undef FRAGS_
}

// ---------------------------------------------------------------------------
// Dual-A ring core: one block = 256(i) x 128(v/j); 3-slot LDS ring,
// distance-2 prefetch, counted vmcnt(6) (T3+T4: never drain to 0 mid-loop).
// Per K-step: 6 gloads + 12 ds_read_b128 + 32 MFMA + ONE raw s_barrier.
// Slot safety: STG(t+2) overwrites slot (t+2)%3, last read at step t-1 and
// all its ds_reads were consumed by MFMAs before that wave entered the step-t
// barrier; gload LDS-writes happen after issue (post-barrier). Read safety:
// each wave waits vmcnt(6) (own loads for t landed) BEFORE the barrier, so
// after the barrier all waves' t-loads are visible (m201 pattern).
// Granule swizzle slot = g ^ ((row>>1)&3) on BOTH staged source and frag
// read (rule #21) -> 0 bank conflicts (verified rounds 3-5).
// REQUIRES: ksteps % 3 == 0 and ksteps >= 6.
template <int LDA, int LDB>
__device__ __forceinline__ void gemm_ring2(const u16* __restrict__ A0,
                                           const u16* __restrict__ A1,
                                           const u16* __restrict__ B, int ksteps,
                                           u16* As0, u16* As1, u16* Bs,
                                           f32x4 (&acc0)[4][4],
                                           f32x4 (&acc1)[4][4], int t) {
  const int lane = t & 63, w = t >> 6, wr = w >> 1, wc = w & 1;
  const int rl = lane & 15;
  const int gsw = (((lane >> 4) ^ ((rl >> 1) & 3)) * 8);
  const int srow = 16 * w + (lane >> 2);
  const int sg = (((lane & 3) ^ ((lane >> 3) & 3)) * 8);
  const size_t gaBase = (size_t)srow * LDA + sg;
  const size_t gbBase = (size_t)srow * LDB + sg;
  const int wof = w * 512;  // wave-uniform LDS sub-base (u16 units)

#define STG3_(ss, kt)                                                   \
  {                                                                     \
    const u16* ga0_ = A0 + gaBase + (size_t)(kt) * 32;                  \
    const u16* ga1_ = A1 + gaBase + (size_t)(kt) * 32;                  \
    const u16* gb_ = B + gbBase + (size_t)(kt) * 32;                    \
    gload16(ga0_, As0 + (ss) * 4096 + wof);                             \
    gload16(ga0_ + (size_t)64 * LDA, As0 + (ss) * 4096 + wof + 2048);   \
    gload16(ga1_, As1 + (ss) * 4096 + wof);                            \
    gload16(ga1_ + (size_t)64 * LDA, As1 + (ss) * 4096 + wof + 2048);   \
    gload16(gb_, Bs + (ss) * 4096 + wof);                              \
    gload16(gb_ + (size_t)64 * LDB, Bs + (ss) * 4096 + wof + 2048);     \
  }

#define FRAGS3_(ss)                                                     \
  half8 af0[4], af1[4], bf[4];                                          \
  _Pragma("unroll") for (int n = 0; n < 4; ++n)                         \
      bf[n] = *(const half8*)(Bs + (ss) * 4096 +                        \
                              (wc * 64 + n * 16 + rl) * 32 + gsw);      \
  _Pragma("unroll") for (int m = 0; m < 4; ++m)                         \
      af0[m] = *(const half8*)(As0 + (ss) * 4096 +                      \
                               (wr * 64 + m * 16 + rl) * 32 + gsw);     \
  _Pragma("unroll") for (int m = 0; m < 4; ++m)                         \
      af1[m] = *(const half8*)(As1 + (ss) * 4096 +                      \
                               (wr * 64 + m * 16 + rl) * 32 + gsw);

#define MFMA32_                                                         \
  __builtin_amdgcn_s_setprio(1);                                        \
  _Pragma("unroll") for (int m = 0; m < 4; ++m)                         \
      _Pragma("unroll") for (int n = 0; n < 4; ++n)                     \
          acc0[m][n] = __builtin_amdgcn_mfma_f32_16x16x32_f16(          \
              af0[m], bf[n], acc0[m][n], 0, 0, 0);                      \
  _Pragma("unroll") for (int m = 0; m < 4; ++m)                         \
      _Pragma("unroll") for (int n = 0; n < 4; ++n)                     \
          acc1[m][n] = __builtin_amdgcn_mfma_f32_16x16x32_f16(          \
              af1[m], bf[n], acc1[m][n], 0, 0, 0);                      \
  __builtin_amdgcn_s_setprio(0);

#define STEPF_(ss, kt)                                                  \
  asm volatile("s_waitcnt vmcnt(6)" ::: "memory");                      \
  __builtin_amdgcn_s_barrier();                                         \
  __builtin_amdgcn_sched_barrier(0);                                    \
  STG3_(((ss) + 2) % 3, (kt) + 2);                                      \
  { FRAGS3_(ss) MFMA32_ }

#define STEPL6_(ss)                                                     \
  asm volatile("s_waitcnt vmcnt(6)" ::: "memory");                      \
  __builtin_amdgcn_s_barrier();                                         \
  __builtin_amdgcn_sched_barrier(0);                                    \
  { FRAGS3_(ss) MFMA32_ }

#define STEPL0_(ss)                                                     \
  asm volatile("s_waitcnt vmcnt(0)" ::: "memory");                      \
  __builtin_amdgcn_s_barrier();                                         \
  __builtin_amdgcn_sched_barrier(0);                                    \
  { FRAGS3_(ss) MFMA32_ }

  STG3_(0, 0);
  STG3_(1, 1);
  const int nTrip = ksteps / 3;
  for (int u = 0; u < nTrip - 1; ++u) {
    const int kt = 3 * u;
    STEPF_(0, kt);
    STEPF_(1, kt + 1);
    STEPF_(2, kt + 2);
  }
  // tail triple: kt = ksteps-3 stages slot 2 (= (ksteps-1)%3) then drains
  STEPF_(0, ksteps - 3);
  STEPL6_(1);
  STEPL0_(2);
#undef STG3_
#undef FRAGS3_
#undef MFMA32_
#undef STEPF_
#undef STEPL6_
#undef STEPL0_
}

// K4: sims[bk][i] += sum_j relu(content[bk] @ Wg[b]^T). grid (8,4,32):
// x = j-tile (8), y = i-pair (4: 256 rows/block), z = bk. Dual-A ring core.
__global__ __launch_bounds__(256, 2) void k_sims(const u16* __restrict__ cbf,
                                                 const u16* __restrict__ Wg,
                                                 float* __restrict__ sims) {
  __shared__ __align__(16) u16 As0[3 * 4096];
  __shared__ __align__(16) u16 As1[3 * 4096];
  __shared__ __align__(16) u16 Bs[3 * 4096];
  const int bk = blockIdx.z, b = bk >> 4;
  const int t = threadIdx.x;
  const int i0 = blockIdx.y * 256;
  const u16* A0 = cbf + (size_t)bk * SEQ * DIM + (size_t)i0 * DIM;
  const u16* A1 = A0 + (size_t)128 * DIM;
  const u16* B = Wg + (size_t)b * SEQ * DIM + (size_t)(blockIdx.x * 128) * DIM;
  f32x4 acc0[4][4] = {}, acc1[4][4] = {};
  gemm_ring2<DIM, DIM>(A0, A1, B, DIM / 32, As0, As1, Bs, acc0, acc1, t);
  const int lane = t & 63, w = t >> 6, wr = w >> 1;
  const int rg = lane >> 4, cl = lane & 15;
#pragma unroll
  for (int m = 0; m < 4; ++m) {
#pragma unroll
    for (int r = 0; r < 4; ++r) {
      float s0 = 0.f, s1 = 0.f;
#pragma unroll
      for (int n = 0; n < 4; ++n) {
        s0 += fmaxf(acc0[m][n][r], 0.f);
        s1 += fmaxf(acc1[m][n][r], 0.f);
      }
      s0 += __shfl_xor(s0, 1); s1 += __shfl_xor(s1, 1);
      s0 += __shfl_xor(s0, 2); s1 += __shfl_xor(s1, 2);
      s0 += __shfl_xor(s0, 4); s1 += __shfl_xor(s1, 4);
      s0 += __shfl_xor(s0, 8); s1 += __shfl_xor(s1, 8);
      if (cl == 0) {
        const int i = i0 + wr * 64 + m * 16 + rg * 4 + r;
        atomicAdd(&sims[(size_t)bk * SEQ + i], s0);
        atomicAdd(&sims[(size_t)bk * SEQ + i + 128], s1);
      }
    }
  }
}

// K5: wtsT[bk][j] = cw*score + (1-score). grid (4,32), block 256
__global__ void k_weights(const float* __restrict__ sims, const int* __restrict__ ids,
                          const float* __restrict__ cw, float* __restrict__ wtsT) {
  const int j = blockIdx.x * 256 + threadIdx.x;
  const int bk = blockIdx.y;
  const int b = bk >> 4, k = bk & 15;
  const float sm = sims[(size_t)bk * SEQ + j];
  float score = 1.f / (1.f + __expf(0.1f * sm - 6.f));  // sigmoid(-0.1*s + 6)
  score *= 1.f + (float)j * 0.01f;
  const int id = ids[b * SEQ + j];
  const float c = cw[(size_t)id * NV + k];
  wtsT[(size_t)bk * SEQ + j] = c * score + (1.f - score);
}

// K6: ctxw[bk][i][j] = f16(ctx * wtsT[bk][j]). grid 32768, block 256
__global__ void k_ctx(const float* __restrict__ ctx, const float* __restrict__ wtsT,
                      u16* __restrict__ ctxw) {
  const size_t i = ((size_t)blockIdx.x * 256 + threadIdx.x) * 4;
  const float4 c = *(const float4*)(ctx + i);
  const size_t bk = i >> 20;           // / (SEQ*SEQ)
  const int j = (int)(i & (SEQ - 1));  // column within row
  const float4 wv = *(const float4*)(wtsT + bk * SEQ + j);
  *(uint2*)(ctxw + i) =
      make_uint2(pk2h(c.x * wv.x, c.y * wv.y), pk2h(c.z * wv.z, c.w * wv.w));
}

// K7: hidden partials. grid (6, 8, 8): x=d-tile, y=i-tile, z=b*4+g
__global__ __launch_bounds__(256) void k_hidden(const u16* __restrict__ ctxw,
                                                const u16* __restrict__ cT,
                                                float* __restrict__ part) {
  __shared__ __align__(16) u16 As[2 * 128 * 32];
  __shared__ __align__(16) u16 Bs[2 * 128 * 32];
  const int z = blockIdx.z;
  const int b = z >> 2, g = z & 3;
  const int i0 = blockIdx.y * 128, d0 = blockIdx.x * 128;
  const int t = threadIdx.x;
  f32x4 acc[4][4] = {};
  for (int kk = 0; kk < 4; ++kk) {
    const int sense = g * 4 + kk;
    const u16* A = ctxw + ((size_t)(b * NV + sense) * SEQ + i0) * SEQ;
    const u16* B = cT + ((size_t)(b * NV + sense) * DIM + d0) * SEQ;
    gemm_core<SEQ, SEQ>(A, B, SEQ / 32, As, Bs, acc, t);
    __syncthreads();  // tail reads done before next call restages buf0
  }
  const int lane = t & 63, w = t >> 6, wr = w >> 1, wc = w & 1;
  const int rg = lane >> 4, cl = lane & 15;
  float* P = part + ((size_t)(g * BSZ + b) * SEQ + i0) * DIM + d0;
#pragma unroll
  for (int m = 0; m < 4; ++m)
#pragma unroll
    for (int n = 0; n < 4; ++n)
#pragma unroll
      for (int r = 0; r < 4; ++r)
        P[(size_t)(wr * 64 + m * 16 + rg * 4 + r) * DIM + wc * 64 + n * 16 + cl] =
            acc[m][n][r];
}

// K8: hid = f16(sum_g part[g]). grid 1536, block 256
__global__ void k_reduce(const float* __restrict__ part, u16* __restrict__ hid) {
  const size_t i = ((size_t)blockIdx.x * 256 + threadIdx.x) * 4;
  const size_t NHID = (size_t)BSZ * SEQ * DIM;
  float4 s = {0.f, 0.f, 0.f, 0.f};
#pragma unroll
  for (int g = 0; g < 4; ++g) {
    const float4 p = *(const float4*)(part + (size_t)g * NHID + i);
    s.x += p.x; s.y += p.y; s.z += p.z; s.w += p.w;
  }
  *(uint2*)(hid + i) = make_uint2(pk2h(s.x, s.y), pk2h(s.z, s.w));
}

// K9: logits = hid @ Wb^T. Dual-A ring: block = 256(i) x 128(v). Grid 3144 =
// 8 i-pairs x 393 v-tiles, XCD-swizzled (3144 % 8 == 0). Plain stores (NT
// caused 2x write amplification in round 4 — row stride not 64B-aligned).
__global__ __launch_bounds__(256, 2) void k_logits(const u16* __restrict__ hid,
                                                   const u16* __restrict__ Wb,
                                                   float* __restrict__ out) {
  __shared__ __align__(16) u16 As0[3 * 4096];
  __shared__ __align__(16) u16 As1[3 * 4096];
  __shared__ __align__(16) u16 Bs[3 * 4096];
  const int bid = blockIdx.x;
  const int swz = (bid & 7) * 393 + (bid >> 3);
  const int it = swz & 7, vt = swz >> 3;
  const int i0 = it * 256, v0 = vt * 128;
  const int t = threadIdx.x;
  const u16* A0 = hid + (size_t)i0 * DIM;
  const u16* A1 = A0 + (size_t)128 * DIM;
  const u16* B = Wb + (size_t)v0 * DIM;
  f32x4 acc0[4][4] = {}, acc1[4][4] = {};
  gemm_ring2<DIM, DIM>(A0, A1, B, DIM / 32, As0, As1, Bs, acc0, acc1, t);
  const int lane = t & 63, w = t >> 6, wr = w >> 1, wc = w & 1;
  const int rg = lane >> 4, cl = lane & 15;
#pragma unroll
  for (int m = 0; m < 4; ++m)
#pragma unroll
    for (int n = 0; n < 4; ++n) {
      const int vv = v0 + wc * 64 + n * 16 + cl;
      if (vv < VOC) {
        const int i = i0 + wr * 64 + m * 16 + rg * 4;
#pragma unroll
        for (int r = 0; r < 4; ++r)
          out[(size_t)(i + r) * VOC + vv] = acc0[m][n][r];
#pragma unroll
        for (int r = 0; r < 4; ++r)
          out[(size_t)(i + 128 + r) * VOC + vv] = acc1[m][n][r];
      }
    }
}

// ---------------------------------------------------------------------------
extern "C" void kernel_launch(void* const* d_in, const int* in_sizes, int n_in,
                              void* d_out, int out_size, void* d_ws, size_t ws_size,
                              hipStream_t stream) {
  const int* ids = (const int*)d_in[0];
  const float* content = (const float*)d_in[1];
  const float* ctx = (const float*)d_in[2];
  const float* W = (const float*)d_in[3];
  const float* cw = (const float*)d_in[4];
  float* out = (float*)d_out;
  char* ws = (char*)d_ws;

  // workspace layout (bytes, all 256-aligned); total 248,446,976
  u16* cbf  = (u16*)(ws);                  // 50,331,648  [32][S][D] f16
  u16* cT   = (u16*)(ws + 50331648);       // 50,331,648  [32][D][S] f16
  u16* Wb   = (u16*)(ws + 100663296);      // 77,266,944  [VOCP][D] f16
  u16* Wg   = (u16*)(ws + 177930240);      //  3,145,728  [B][S][D] f16
  u16* ctxw = (u16*)(ws + 181075968);      // 67,108,864  [32][S][S] f16
  float* sims = (float*)(ws + 248184832);  //    131,072  [32][S] f32
  float* wtsT = (float*)(ws + 248315904);  //    131,072  [32][S] f32
  // aliases (safe by dataflow: source buffer dead before alias first written)
  float* part = (float*)cbf;               // 25,165,824  [4][B][S][D] f32
  u16* hid = Wg;                           //  3,145,728  [B*S][D] f16

  k_prep_content<<<dim3(DIM / 32, SEQ / 32, BSZ * NV), dim3(32, 8), 0, stream>>>(
      content, cbf, cT);
  k_prep_w<<<VOCP, 192, 0, stream>>>(W, Wb);
  k_gather<<<dim3(SEQ, BSZ), 192, 0, stream>>>(ids, Wb, Wg);
  k_zero<<<128, 256, 0, stream>>>(sims, BSZ * NV * SEQ);
  k_sims<<<dim3(8, 4, BSZ * NV), 256, 0, stream>>>(cbf, Wg, sims);
  k_weights<<<dim3(4, BSZ * NV), 256, 0, stream>>>(sims, ids, cw, wtsT);
  k_ctx<<<32768, 256, 0, stream>>>(ctx, wtsT, ctxw);
  k_hidden<<<dim3(6, 8, 8), 256, 0, stream>>>(ctxw, cT, part);
  k_reduce<<<1536, 256, 0, stream>>>(part, hid);
  k_logits<<<8 * 393, 256, 0, stream>>>(hid, Wb, out);
}

// Round 7
// 587.059 us; speedup vs baseline: 1.3548x; 1.0075x over previous
//
#include <hip/hip_runtime.h>
#include <cstdint>
#include <cstddef>

#define BSZ 2
#define NV 16
#define SEQ 1024
#define DIM 768
#define VOC 50257
#define VOCP 50304   // padded to multiple of 128

typedef unsigned int u32;
typedef unsigned short u16;
typedef _Float16 half8 __attribute__((ext_vector_type(8)));
typedef float f32x4 __attribute__((ext_vector_type(4)));

__device__ __forceinline__ u16 f2h(float f) {
  return __builtin_bit_cast(unsigned short, (_Float16)f);
}
__device__ __forceinline__ u32 pk2h(float a, float b) {
  return (u32)f2h(a) | ((u32)f2h(b) << 16);
}

// async global->LDS, 16B per lane; LDS dest = wave-uniform base + lane*16
__device__ __forceinline__ void gload16(const u16* g, u16* l) {
  __builtin_amdgcn_global_load_lds(
      (const __attribute__((address_space(1))) void*)g,
      (__attribute__((address_space(3))) void*)l, 16, 0, 0);
}

// ---------------------------------------------------------------------------
// K1: content f32 -> f16 (normal + transposed per (b,k) slice)
__global__ void k_prep_content(const float* __restrict__ content,
                               u16* __restrict__ cbf, u16* __restrict__ cT) {
  __shared__ u16 tile[32][33];
  const int bk = blockIdx.z;
  const int d0 = blockIdx.x * 32, j0 = blockIdx.y * 32;
  const float* src = content + (size_t)bk * SEQ * DIM;
  u16* dst = cbf + (size_t)bk * SEQ * DIM;
  u16* dstT = cT + (size_t)bk * DIM * SEQ;
  const int c = threadIdx.x;
#pragma unroll
  for (int rr = 0; rr < 4; ++rr) {
    const int r = threadIdx.y * 4 + rr;
    const float v = src[(size_t)(j0 + r) * DIM + d0 + c];
    const u16 bv = f2h(v);
    dst[(size_t)(j0 + r) * DIM + d0 + c] = bv;
    tile[r][c] = bv;
  }
  __syncthreads();
#pragma unroll
  for (int rr = 0; rr < 4; ++rr) {
    const int r = threadIdx.y * 4 + rr;       // d-local
    dstT[(size_t)(d0 + r) * SEQ + j0 + c] = tile[c][r];
  }
}

// K2: lm_head_weight f32 -> f16, padded rows zeroed. grid VOCP, block 192
__global__ void k_prep_w(const float* __restrict__ W, u16* __restrict__ Wb) {
  const int v = blockIdx.x;
  const int c = threadIdx.x * 4;
  u32 lo, hi;
  if (v < VOC) {
    const float4 f = *(const float4*)(W + (size_t)v * DIM + c);
    lo = pk2h(f.x, f.y); hi = pk2h(f.z, f.w);
  } else {
    lo = 0u; hi = 0u;
  }
  *(uint2*)(Wb + (size_t)v * DIM + c) = make_uint2(lo, hi);
}

// K3: gather Wg[b][j][:] = Wb[ids[b][j]][:]  grid (SEQ, BSZ), block 192
__global__ void k_gather(const int* __restrict__ ids, const u16* __restrict__ Wb,
                         u16* __restrict__ Wg) {
  const int b = blockIdx.y, j = blockIdx.x;
  const int row = ids[b * SEQ + j];
  const int c = threadIdx.x * 4;
  *(uint2*)(Wg + ((size_t)b * SEQ + j) * DIM + c) =
      *(const uint2*)(Wb + (size_t)row * DIM + c);
}

__global__ void k_zero(float* __restrict__ p, int n) {
  const int i = blockIdx.x * 256 + threadIdx.x;
  if (i < n) p[i] = 0.f;
}

// ---------------------------------------------------------------------------
// 128x128 2-phase core (round-3, verified) — used by k_hidden.
template <int LDA, int LDB>
__device__ __forceinline__ void gemm_core(const u16* __restrict__ A,
                                          const u16* __restrict__ B, int ksteps,
                                          u16* As, u16* Bs, f32x4 (&acc)[4][4],
                                          int t) {
  const int lane = t & 63, w = t >> 6, wr = w >> 1, wc = w & 1;
  const int rl = lane & 15;
  const int gsw = (((lane >> 4) ^ ((rl >> 1) & 3)) * 8);  // read granule (u16)
  const int srow = 16 * w + (lane >> 2);                  // staging row 0..63
  const int sg = (((lane & 3) ^ ((lane >> 3) & 3)) * 8);  // staged src granule
  const size_t gaBase = (size_t)srow * LDA + sg;
  const size_t gbBase = (size_t)srow * LDB + sg;
  u16* lA = As + w * 512;  // wave-uniform LDS base (+bb*4096)
  u16* lB = Bs + w * 512;

#define STAGE_(bb, kt)                                                  \
  {                                                                     \
    const u16* ga_ = A + gaBase + (size_t)(kt) * 32;                    \
    const u16* gb_ = B + gbBase + (size_t)(kt) * 32;                    \
    gload16(ga_, lA + (bb) * 4096);                                     \
    gload16(ga_ + (size_t)64 * LDA, lA + (bb) * 4096 + 2048);           \
    gload16(gb_, lB + (bb) * 4096);                                     \
    gload16(gb_ + (size_t)64 * LDB, lB + (bb) * 4096 + 2048);           \
  }

#define FRAGS_(bb)                                                      \
  half8 af[4], bf[4];                                                   \
  _Pragma("unroll") for (int m = 0; m < 4; ++m)                         \
      af[m] = *(const half8*)(As + (bb) * 4096 +                        \
                              (wr * 64 + m * 16 + rl) * 32 + gsw);      \
  _Pragma("unroll") for (int n = 0; n < 4; ++n)                         \
      bf[n] = *(const half8*)(Bs + (bb) * 4096 +                        \
                              (wc * 64 + n * 16 + rl) * 32 + gsw);      \
  _Pragma("unroll") for (int m = 0; m < 4; ++m)                         \
      _Pragma("unroll") for (int n = 0; n < 4; ++n)                     \
          acc[m][n] = __builtin_amdgcn_mfma_f32_16x16x32_f16(           \
              af[m], bf[n], acc[m][n], 0, 0, 0);

  STAGE_(0, 0);
  __syncthreads();          // buf0 ready
  int cur = 0;
  for (int kt = 0; kt < ksteps - 1; ++kt) {
    STAGE_(cur ^ 1, kt + 1);  // issue next tile early
    { FRAGS_(cur); }
    __syncthreads();
    cur ^= 1;
  }
  { FRAGS_(cur); }            // tail, no barrier
#undef STAGE_
#undef FRAGS_
}

// ---------------------------------------------------------------------------
// Dual-A ring core (round-6, verified) — used by k_sims.
template <int LDA, int LDB>
__device__ __forceinline__ void gemm_ring2(const u16* __restrict__ A0,
                                           const u16* __restrict__ A1,
                                           const u16* __restrict__ B, int ksteps,
                                           u16* As0, u16* As1, u16* Bs,
                                           f32x4 (&acc0)[4][4],
                                           f32x4 (&acc1)[4][4], int t) {
  const int lane = t & 63, w = t >> 6, wr = w >> 1, wc = w & 1;
  const int rl = lane & 15;
  const int gsw = (((lane >> 4) ^ ((rl >> 1) & 3)) * 8);
  const int srow = 16 * w + (lane >> 2);
  const int sg = (((lane & 3) ^ ((lane >> 3) & 3)) * 8);
  const size_t gaBase = (size_t)srow * LDA + sg;
  const size_t gbBase = (size_t)srow * LDB + sg;
  const int wof = w * 512;  // wave-uniform LDS sub-base (u16 units)

#define STG3_(ss, kt)                                                   \
  {                                                                     \
    const u16* ga0_ = A0 + gaBase + (size_t)(kt) * 32;                  \
    const u16* ga1_ = A1 + gaBase + (size_t)(kt) * 32;                  \
    const u16* gb_ = B + gbBase + (size_t)(kt) * 32;                    \
    gload16(ga0_, As0 + (ss) * 4096 + wof);                             \
    gload16(ga0_ + (size_t)64 * LDA, As0 + (ss) * 4096 + wof + 2048);   \
    gload16(ga1_, As1 + (ss) * 4096 + wof);                            \
    gload16(ga1_ + (size_t)64 * LDA, As1 + (ss) * 4096 + wof + 2048);   \
    gload16(gb_, Bs + (ss) * 4096 + wof);                              \
    gload16(gb_ + (size_t)64 * LDB, Bs + (ss) * 4096 + wof + 2048);     \
  }

#define FRAGS3_(ss)                                                     \
  half8 af0[4], af1[4], bf[4];                                          \
  _Pragma("unroll") for (int n = 0; n < 4; ++n)                         \
      bf[n] = *(const half8*)(Bs + (ss) * 4096 +                        \
                              (wc * 64 + n * 16 + rl) * 32 + gsw);      \
  _Pragma("unroll") for (int m = 0; m < 4; ++m)                         \
      af0[m] = *(const half8*)(As0 + (ss) * 4096 +                      \
                               (wr * 64 + m * 16 + rl) * 32 + gsw);     \
  _Pragma("unroll") for (int m = 0; m < 4; ++m)                         \
      af1[m] = *(const half8*)(As1 + (ss) * 4096 +                      \
                               (wr * 64 + m * 16 + rl) * 32 + gsw);

#define MFMA32_                                                         \
  __builtin_amdgcn_s_setprio(1);                                        \
  _Pragma("unroll") for (int m = 0; m < 4; ++m)                         \
      _Pragma("unroll") for (int n = 0; n < 4; ++n)                     \
          acc0[m][n] = __builtin_amdgcn_mfma_f32_16x16x32_f16(          \
              af0[m], bf[n], acc0[m][n], 0, 0, 0);                      \
  _Pragma("unroll") for (int m = 0; m < 4; ++m)                         \
      _Pragma("unroll") for (int n = 0; n < 4; ++n)                     \
          acc1[m][n] = __builtin_amdgcn_mfma_f32_16x16x32_f16(          \
              af1[m], bf[n], acc1[m][n], 0, 0, 0);                      \
  __builtin_amdgcn_s_setprio(0);

#define STEPF_(ss, kt)                                                  \
  asm volatile("s_waitcnt vmcnt(6)" ::: "memory");                      \
  __builtin_amdgcn_s_barrier();                                         \
  __builtin_amdgcn_sched_barrier(0);                                    \
  STG3_(((ss) + 2) % 3, (kt) + 2);                                      \
  { FRAGS3_(ss) MFMA32_ }

#define STEPL6_(ss)                                                     \
  asm volatile("s_waitcnt vmcnt(6)" ::: "memory");                      \
  __builtin_amdgcn_s_barrier();                                         \
  __builtin_amdgcn_sched_barrier(0);                                    \
  { FRAGS3_(ss) MFMA32_ }

#define STEPL0_(ss)                                                     \
  asm volatile("s_waitcnt vmcnt(0)" ::: "memory");                      \
  __builtin_amdgcn_s_barrier();                                         \
  __builtin_amdgcn_sched_barrier(0);                                    \
  { FRAGS3_(ss) MFMA32_ }

  STG3_(0, 0);
  STG3_(1, 1);
  const int nTrip = ksteps / 3;
  for (int u = 0; u < nTrip - 1; ++u) {
    const int kt = 3 * u;
    STEPF_(0, kt);
    STEPF_(1, kt + 1);
    STEPF_(2, kt + 2);
  }
  STEPF_(0, ksteps - 3);
  STEPL6_(1);
  STEPL0_(2);
#undef STG3_
#undef FRAGS3_
#undef MFMA32_
#undef STEPF_
#undef STEPL6_
#undef STEPL0_
}

// K4: sims[bk][i] += sum_j relu(content[bk] @ Wg[b]^T). grid (8,4,32)
__global__ __launch_bounds__(256, 2) void k_sims(const u16* __restrict__ cbf,
                                                 const u16* __restrict__ Wg,
                                                 float* __restrict__ sims) {
  __shared__ __align__(16) u16 As0[3 * 4096];
  __shared__ __align__(16) u16 As1[3 * 4096];
  __shared__ __align__(16) u16 Bs[3 * 4096];
  const int bk = blockIdx.z, b = bk >> 4;
  const int t = threadIdx.x;
  const int i0 = blockIdx.y * 256;
  const u16* A0 = cbf + (size_t)bk * SEQ * DIM + (size_t)i0 * DIM;
  const u16* A1 = A0 + (size_t)128 * DIM;
  const u16* B = Wg + (size_t)b * SEQ * DIM + (size_t)(blockIdx.x * 128) * DIM;
  f32x4 acc0[4][4] = {}, acc1[4][4] = {};
  gemm_ring2<DIM, DIM>(A0, A1, B, DIM / 32, As0, As1, Bs, acc0, acc1, t);
  const int lane = t & 63, w = t >> 6, wr = w >> 1;
  const int rg = lane >> 4, cl = lane & 15;
#pragma unroll
  for (int m = 0; m < 4; ++m) {
#pragma unroll
    for (int r = 0; r < 4; ++r) {
      float s0 = 0.f, s1 = 0.f;
#pragma unroll
      for (int n = 0; n < 4; ++n) {
        s0 += fmaxf(acc0[m][n][r], 0.f);
        s1 += fmaxf(acc1[m][n][r], 0.f);
      }
      s0 += __shfl_xor(s0, 1); s1 += __shfl_xor(s1, 1);
      s0 += __shfl_xor(s0, 2); s1 += __shfl_xor(s1, 2);
      s0 += __shfl_xor(s0, 4); s1 += __shfl_xor(s1, 4);
      s0 += __shfl_xor(s0, 8); s1 += __shfl_xor(s1, 8);
      if (cl == 0) {
        const int i = i0 + wr * 64 + m * 16 + rg * 4 + r;
        atomicAdd(&sims[(size_t)bk * SEQ + i], s0);
        atomicAdd(&sims[(size_t)bk * SEQ + i + 128], s1);
      }
    }
  }
}

// K5: wtsT[bk][j] = cw*score + (1-score). grid (4,32), block 256
__global__ void k_weights(const float* __restrict__ sims, const int* __restrict__ ids,
                          const float* __restrict__ cw, float* __restrict__ wtsT) {
  const int j = blockIdx.x * 256 + threadIdx.x;
  const int bk = blockIdx.y;
  const int b = bk >> 4, k = bk & 15;
  const float sm = sims[(size_t)bk * SEQ + j];
  float score = 1.f / (1.f + __expf(0.1f * sm - 6.f));  // sigmoid(-0.1*s + 6)
  score *= 1.f + (float)j * 0.01f;
  const int id = ids[b * SEQ + j];
  const float c = cw[(size_t)id * NV + k];
  wtsT[(size_t)bk * SEQ + j] = c * score + (1.f - score);
}

// K6: ctxw[bk][i][j] = f16(ctx * wtsT[bk][j]). grid 32768, block 256
__global__ void k_ctx(const float* __restrict__ ctx, const float* __restrict__ wtsT,
                      u16* __restrict__ ctxw) {
  const size_t i = ((size_t)blockIdx.x * 256 + threadIdx.x) * 4;
  const float4 c = *(const float4*)(ctx + i);
  const size_t bk = i >> 20;           // / (SEQ*SEQ)
  const int j = (int)(i & (SEQ - 1));  // column within row
  const float4 wv = *(const float4*)(wtsT + bk * SEQ + j);
  *(uint2*)(ctxw + i) =
      make_uint2(pk2h(c.x * wv.x, c.y * wv.y), pk2h(c.z * wv.z, c.w * wv.w));
}

// K7: hidden partials. grid (6, 8, 8): x=d-tile, y=i-tile, z=b*4+g
__global__ __launch_bounds__(256) void k_hidden(const u16* __restrict__ ctxw,
                                                const u16* __restrict__ cT,
                                                float* __restrict__ part) {
  __shared__ __align__(16) u16 As[2 * 128 * 32];
  __shared__ __align__(16) u16 Bs[2 * 128 * 32];
  const int z = blockIdx.z;
  const int b = z >> 2, g = z & 3;
  const int i0 = blockIdx.y * 128, d0 = blockIdx.x * 128;
  const int t = threadIdx.x;
  f32x4 acc[4][4] = {};
  for (int kk = 0; kk < 4; ++kk) {
    const int sense = g * 4 + kk;
    const u16* A = ctxw + ((size_t)(b * NV + sense) * SEQ + i0) * SEQ;
    const u16* B = cT + ((size_t)(b * NV + sense) * DIM + d0) * SEQ;
    gemm_core<SEQ, SEQ>(A, B, SEQ / 32, As, Bs, acc, t);
    __syncthreads();  // tail reads done before next call restages buf0
  }
  const int lane = t & 63, w = t >> 6, wr = w >> 1, wc = w & 1;
  const int rg = lane >> 4, cl = lane & 15;
  float* P = part + ((size_t)(g * BSZ + b) * SEQ + i0) * DIM + d0;
#pragma unroll
  for (int m = 0; m < 4; ++m)
#pragma unroll
    for (int n = 0; n < 4; ++n)
#pragma unroll
      for (int r = 0; r < 4; ++r)
        P[(size_t)(wr * 64 + m * 16 + rg * 4 + r) * DIM + wc * 64 + n * 16 + cl] =
            acc[m][n][r];
}

// K8: hid = f16(sum_g part[g]). grid 1536, block 256
__global__ void k_reduce(const float* __restrict__ part, u16* __restrict__ hid) {
  const size_t i = ((size_t)blockIdx.x * 256 + threadIdx.x) * 4;
  const size_t NHID = (size_t)BSZ * SEQ * DIM;
  float4 s = {0.f, 0.f, 0.f, 0.f};
#pragma unroll
  for (int g = 0; g < 4; ++g) {
    const float4 p = *(const float4*)(part + (size_t)g * NHID + i);
    s.x += p.x; s.y += p.y; s.z += p.z; s.w += p.w;
  }
  *(uint2*)(hid + i) = make_uint2(pk2h(s.x, s.y), pk2h(s.z, s.w));
}

// ---------------------------------------------------------------------------
// K9: logits = hid @ Wb^T — m201-style 256x256, BK=64, 512 thr (8 waves 2Mx4N,
// 128x64 out/wave = 8x4 frags). LDS = 8 half-slots x 16 KB (A/B K-slices of
// 32 k-cols x 256 rows). 24 super-phases (12 K-tiles x 2 K-slices); staging
// leads consumption by 3 super-phases (12 loads in flight); per super-phase:
//   vmcnt(8) -> s_barrier -> stage 2 halves (4 gloads) -> 12 ds_read -> 32 MFMA
// vmcnt(8): the 8 newest outstanding loads are always the last 2 super-phases'
// stages, so <=8 outstanding proves the current slices landed (never 0 until
// the peeled tail: 8,8,4,0). Slot h&7 reuse is one barrier after last reader.
// Granule swizzle g^=(row>>1)&3 on BOTH staged source and frag read.
// Grid 1576 = 8 i-tiles x 197 v-tiles (vt=196 clamped: overlap rows recompute
// identical values — benign). XCD-swizzled (1576 % 8 == 0). Plain stores.
__global__ __launch_bounds__(512, 2) void k_logits(const u16* __restrict__ hid,
                                                   const u16* __restrict__ Wb,
                                                   float* __restrict__ out) {
  __shared__ __align__(16) u16 lds[8 * 8192];  // 128 KB
  const int bid = blockIdx.x;
  const int swz = (bid & 7) * 197 + (bid >> 3);
  const int it = swz & 7, vt = swz >> 3;
  const int i0 = it * 256;
  const int v0 = (vt == 196) ? (VOCP - 256) : vt * 256;
  const int t = threadIdx.x;
  const int lane = t & 63, w = t >> 6;
  const int wm = w >> 2, wn = w & 3;
  const int rl = lane & 15, kg = lane >> 4;
  const int gsw = (kg ^ ((rl >> 1) & 3)) * 8;     // frag read granule (u16)
  // staging: 512 thr cover 128 rows x 4 granules; two gloads (rows, rows+128)
  const int gi = w * 64 + lane;                   // 0..511
  const int srow = gi >> 2;                       // 0..127
  const int sgr = ((gi & 3) ^ ((srow >> 1) & 3)) * 8;  // pre-swizzled src (u16)
  const u16* Abase = hid + (size_t)i0 * DIM;
  const u16* Bbase = Wb + (size_t)v0 * DIM;
  u16* ldst = lds + w * 512 + lane * 8;           // + slot*8192 (+4096 q=1)

#define STG(slot, base, koff)                                         \
  {                                                                   \
    const u16* s_ = (base) + (size_t)srow * DIM + (koff) + sgr;       \
    gload16(s_, ldst + (slot) * 8192);                                \
    gload16(s_ + (size_t)128 * DIM, ldst + (slot) * 8192 + 4096);     \
  }

#define COMPUTE(sA, sB)                                               \
  {                                                                   \
    half8 bf[4], af[8];                                               \
    _Pragma("unroll") for (int n = 0; n < 4; ++n)                     \
        bf[n] = *(const half8*)(lds + (sB) * 8192 +                   \
                                (wn * 64 + n * 16 + rl) * 32 + gsw);  \
    _Pragma("unroll") for (int m = 0; m < 8; ++m)                     \
        af[m] = *(const half8*)(lds + (sA) * 8192 +                   \
                                (wm * 128 + m * 16 + rl) * 32 + gsw); \
    __builtin_amdgcn_s_setprio(1);                                    \
    _Pragma("unroll") for (int m = 0; m < 8; ++m)                     \
        _Pragma("unroll") for (int n = 0; n < 4; ++n)                 \
            acc[m][n] = __builtin_amdgcn_mfma_f32_16x16x32_f16(       \
                af[m], bf[n], acc[m][n], 0, 0, 0);                    \
    __builtin_amdgcn_s_setprio(0);                                    \
  }

#define WAITB(N)                                          \
  asm volatile("s_waitcnt vmcnt(" #N ")" ::: "memory");   \
  __builtin_amdgcn_s_barrier();                           \
  __builtin_amdgcn_sched_barrier(0);

  f32x4 acc[8][4] = {};
  // prologue: halves 0..5 = tile0 {A0,B0,A1,B1} + tile1 {A0,B0}
  STG(0, Abase, 0);
  STG(1, Bbase, 0);
  STG(2, Abase, 32);
  STG(3, Bbase, 32);
  STG(4, Abase, 64);
  STG(5, Bbase, 64);

  for (int tau = 0; tau < 10; ++tau) {
    const int tp = (tau & 1) * 4;
    const int kb = tau * 64;
    // ks0: read slots tp,tp+1; stage A/B-ks1 of tile tau+1
    WAITB(8);
    STG((tp + 6) & 7, Abase, kb + 96);
    STG((tp + 7) & 7, Bbase, kb + 96);
    COMPUTE(tp, tp + 1);
    // ks1: read slots tp+2,tp+3; stage A/B-ks0 of tile tau+2
    WAITB(8);
    STG((tp + 8) & 7, Abase, kb + 128);
    STG((tp + 9) & 7, Bbase, kb + 128);
    COMPUTE(tp + 2, tp + 3);
  }
  // tau=10 (tp=0): stage last halves (tile 11 ks1), then drain
  WAITB(8);
  STG(6, Abase, 736);
  STG(7, Bbase, 736);
  COMPUTE(0, 1);
  WAITB(8);
  COMPUTE(2, 3);
  // tau=11 (tp=4)
  WAITB(4);
  COMPUTE(4, 5);
  WAITB(0);
  COMPUTE(6, 7);
#undef STG
#undef COMPUTE
#undef WAITB

  // epilogue: C col = lane&15 (v), row = (lane>>4)*4 + r (i)
#pragma unroll
  for (int m = 0; m < 8; ++m)
#pragma unroll
    for (int n = 0; n < 4; ++n) {
      const int vv = v0 + wn * 64 + n * 16 + rl;
      if (vv < VOC) {
        const int ib = i0 + wm * 128 + m * 16 + kg * 4;
#pragma unroll
        for (int r = 0; r < 4; ++r)
          out[(size_t)(ib + r) * VOC + vv] = acc[m][n][r];
      }
    }
}

// ---------------------------------------------------------------------------
extern "C" void kernel_launch(void* const* d_in, const int* in_sizes, int n_in,
                              void* d_out, int out_size, void* d_ws, size_t ws_size,
                              hipStream_t stream) {
  const int* ids = (const int*)d_in[0];
  const float* content = (const float*)d_in[1];
  const float* ctx = (const float*)d_in[2];
  const float* W = (const float*)d_in[3];
  const float* cw = (const float*)d_in[4];
  float* out = (float*)d_out;
  char* ws = (char*)d_ws;

  // workspace layout (bytes, all 256-aligned); total 248,446,976
  u16* cbf  = (u16*)(ws);                  // 50,331,648  [32][S][D] f16
  u16* cT   = (u16*)(ws + 50331648);       // 50,331,648  [32][D][S] f16
  u16* Wb   = (u16*)(ws + 100663296);      // 77,266,944  [VOCP][D] f16
  u16* Wg   = (u16*)(ws + 177930240);      //  3,145,728  [B][S][D] f16
  u16* ctxw = (u16*)(ws + 181075968);      // 67,108,864  [32][S][S] f16
  float* sims = (float*)(ws + 248184832);  //    131,072  [32][S] f32
  float* wtsT = (float*)(ws + 248315904);  //    131,072  [32][S] f32
  // aliases (safe by dataflow: source buffer dead before alias first written)
  float* part = (float*)cbf;               // 25,165,824  [4][B][S][D] f32
  u16* hid = Wg;                           //  3,145,728  [B*S][D] f16

  k_prep_content<<<dim3(DIM / 32, SEQ / 32, BSZ * NV), dim3(32, 8), 0, stream>>>(
      content, cbf, cT);
  k_prep_w<<<VOCP, 192, 0, stream>>>(W, Wb);
  k_gather<<<dim3(SEQ, BSZ), 192, 0, stream>>>(ids, Wb, Wg);
  k_zero<<<128, 256, 0, stream>>>(sims, BSZ * NV * SEQ);
  k_sims<<<dim3(8, 4, BSZ * NV), 256, 0, stream>>>(cbf, Wg, sims);
  k_weights<<<dim3(4, BSZ * NV), 256, 0, stream>>>(sims, ids, cw, wtsT);
  k_ctx<<<32768, 256, 0, stream>>>(ctx, wtsT, ctxw);
  k_hidden<<<dim3(6, 8, 8), 256, 0, stream>>>(ctxw, cT, part);
  k_reduce<<<1536, 256, 0, stream>>>(part, hid);
  k_logits<<<8 * 197, 512, 0, stream>>>(hid, Wb, out);
}

// Round 8
// 580.572 us; speedup vs baseline: 1.3699x; 1.0112x over previous
//
#include <hip/hip_runtime.h>
#include <cstdint>
#include <cstddef>

#define BSZ 2
#define NV 16
#define SEQ 1024
#define DIM 768
#define VOC 50257
#define VOCP 50304   // padded to multiple of 128

typedef unsigned int u32;
typedef unsigned short u16;
typedef _Float16 half8 __attribute__((ext_vector_type(8)));
typedef float f32x4 __attribute__((ext_vector_type(4)));

__device__ __forceinline__ u16 f2h(float f) {
  return __builtin_bit_cast(unsigned short, (_Float16)f);
}
__device__ __forceinline__ u32 pk2h(float a, float b) {
  return (u32)f2h(a) | ((u32)f2h(b) << 16);
}

// async global->LDS, 16B per lane; LDS dest = wave-uniform base + lane*16
__device__ __forceinline__ void gload16(const u16* g, u16* l) {
  __builtin_amdgcn_global_load_lds(
      (const __attribute__((address_space(1))) void*)g,
      (__attribute__((address_space(3))) void*)l, 16, 0, 0);
}

// ---------------------------------------------------------------------------
// K1: content f32 -> f16 (normal + transposed). 64x64 tiles, float4 loads.
// grid (12, 16, 32), block 256
__global__ void k_prep_content(const float* __restrict__ content,
                               u16* __restrict__ cbf, u16* __restrict__ cT) {
  __shared__ u16 tile[64][70];  // stride 70 u16: phase-2 col reads ~2-way
  const int bk = blockIdx.z;
  const int d0 = blockIdx.x * 64, j0 = blockIdx.y * 64;
  const float* src = content + (size_t)bk * SEQ * DIM;
  u16* dst = cbf + (size_t)bk * SEQ * DIM;
  u16* dstT = cT + (size_t)bk * DIM * SEQ;
  const int c4 = (threadIdx.x & 15) * 4;  // d-local (x4)
  const int r0 = threadIdx.x >> 4;        // 0..15
#pragma unroll
  for (int it = 0; it < 4; ++it) {
    const int r = it * 16 + r0;           // j-local
    const float4 f = *(const float4*)(src + (size_t)(j0 + r) * DIM + d0 + c4);
    const u32 lo = pk2h(f.x, f.y), hi = pk2h(f.z, f.w);
    *(uint2*)(dst + (size_t)(j0 + r) * DIM + d0 + c4) = make_uint2(lo, hi);
    *(u32*)&tile[r][c4] = lo;
    *(u32*)&tile[r][c4 + 2] = hi;
  }
  __syncthreads();
#pragma unroll
  for (int it = 0; it < 4; ++it) {
    const int dd = it * 16 + r0;          // d-local
    const int j4 = c4;                    // j-local (x4)
    const u32 lo = (u32)tile[j4][dd] | ((u32)tile[j4 + 1][dd] << 16);
    const u32 hi = (u32)tile[j4 + 2][dd] | ((u32)tile[j4 + 3][dd] << 16);
    *(uint2*)(dstT + (size_t)(d0 + dd) * SEQ + j0 + j4) = make_uint2(lo, hi);
  }
}

// K2: lm_head_weight f32 -> f16, padded rows zeroed. grid VOCP, block 192
__global__ void k_prep_w(const float* __restrict__ W, u16* __restrict__ Wb) {
  const int v = blockIdx.x;
  const int c = threadIdx.x * 4;
  u32 lo, hi;
  if (v < VOC) {
    const float4 f = *(const float4*)(W + (size_t)v * DIM + c);
    lo = pk2h(f.x, f.y); hi = pk2h(f.z, f.w);
  } else {
    lo = 0u; hi = 0u;
  }
  *(uint2*)(Wb + (size_t)v * DIM + c) = make_uint2(lo, hi);
}

// K3: gather Wg[b][j][:] = Wb[ids[b][j]][:]  grid (SEQ, BSZ), block 192
__global__ void k_gather(const int* __restrict__ ids, const u16* __restrict__ Wb,
                         u16* __restrict__ Wg) {
  const int b = blockIdx.y, j = blockIdx.x;
  const int row = ids[b * SEQ + j];
  const int c = threadIdx.x * 4;
  *(uint2*)(Wg + ((size_t)b * SEQ + j) * DIM + c) =
      *(const uint2*)(Wb + (size_t)row * DIM + c);
}

__global__ void k_zero(float* __restrict__ p, int n) {
  const int i = blockIdx.x * 256 + threadIdx.x;
  if (i < n) p[i] = 0.f;
}

// ---------------------------------------------------------------------------
// Single-A ring core: 128x128 tile, 3-slot LDS ring, distance-2 prefetch,
// counted vmcnt(4) (never 0 mid-loop). ksteps = 32 fixed (SEQ/32).
// Same sync + swizzle discipline as gemm_ring2 (round-6, verified).
template <int LDA, int LDB>
__device__ __forceinline__ void gemm_ring1(const u16* __restrict__ A,
                                           const u16* __restrict__ B,
                                           u16* As, u16* Bs,
                                           f32x4 (&acc)[4][4], int t) {
  const int lane = t & 63, w = t >> 6, wr = w >> 1, wc = w & 1;
  const int rl = lane & 15;
  const int gsw = (((lane >> 4) ^ ((rl >> 1) & 3)) * 8);
  const int srow = 16 * w + (lane >> 2);
  const int sg = (((lane & 3) ^ ((lane >> 3) & 3)) * 8);
  const size_t gaBase = (size_t)srow * LDA + sg;
  const size_t gbBase = (size_t)srow * LDB + sg;
  const int wof = w * 512;

#define STG1_(ss, kt)                                                   \
  {                                                                     \
    const u16* ga_ = A + gaBase + (size_t)(kt) * 32;                    \
    const u16* gb_ = B + gbBase + (size_t)(kt) * 32;                    \
    gload16(ga_, As + (ss) * 4096 + wof);                               \
    gload16(ga_ + (size_t)64 * LDA, As + (ss) * 4096 + wof + 2048);     \
    gload16(gb_, Bs + (ss) * 4096 + wof);                               \
    gload16(gb_ + (size_t)64 * LDB, Bs + (ss) * 4096 + wof + 2048);     \
  }

  STG1_(0, 0);
  STG1_(1, 1);
#pragma unroll 1
  for (int kt = 0; kt < 32; ++kt) {
    if (kt < 31)
      asm volatile("s_waitcnt vmcnt(4)" ::: "memory");
    else
      asm volatile("s_waitcnt vmcnt(0)" ::: "memory");
    __builtin_amdgcn_s_barrier();
    __builtin_amdgcn_sched_barrier(0);
    const int ss = kt % 3;
    if (kt < 30) STG1_((kt + 2) % 3, kt + 2);
    half8 af[4], bf[4];
#pragma unroll
    for (int m = 0; m < 4; ++m)
      af[m] = *(const half8*)(As + ss * 4096 + (wr * 64 + m * 16 + rl) * 32 + gsw);
#pragma unroll
    for (int n = 0; n < 4; ++n)
      bf[n] = *(const half8*)(Bs + ss * 4096 + (wc * 64 + n * 16 + rl) * 32 + gsw);
    __builtin_amdgcn_s_setprio(1);
#pragma unroll
    for (int m = 0; m < 4; ++m)
#pragma unroll
      for (int n = 0; n < 4; ++n)
        acc[m][n] = __builtin_amdgcn_mfma_f32_16x16x32_f16(af[m], bf[n], acc[m][n], 0, 0, 0);
    __builtin_amdgcn_s_setprio(0);
  }
#undef STG1_
}

// ---------------------------------------------------------------------------
// Dual-A ring core (round-6, verified) — used by k_sims.
template <int LDA, int LDB>
__device__ __forceinline__ void gemm_ring2(const u16* __restrict__ A0,
                                           const u16* __restrict__ A1,
                                           const u16* __restrict__ B, int ksteps,
                                           u16* As0, u16* As1, u16* Bs,
                                           f32x4 (&acc0)[4][4],
                                           f32x4 (&acc1)[4][4], int t) {
  const int lane = t & 63, w = t >> 6, wr = w >> 1, wc = w & 1;
  const int rl = lane & 15;
  const int gsw = (((lane >> 4) ^ ((rl >> 1) & 3)) * 8);
  const int srow = 16 * w + (lane >> 2);
  const int sg = (((lane & 3) ^ ((lane >> 3) & 3)) * 8);
  const size_t gaBase = (size_t)srow * LDA + sg;
  const size_t gbBase = (size_t)srow * LDB + sg;
  const int wof = w * 512;

#define STG3_(ss, kt)                                                   \
  {                                                                     \
    const u16* ga0_ = A0 + gaBase + (size_t)(kt) * 32;                  \
    const u16* ga1_ = A1 + gaBase + (size_t)(kt) * 32;                  \
    const u16* gb_ = B + gbBase + (size_t)(kt) * 32;                    \
    gload16(ga0_, As0 + (ss) * 4096 + wof);                             \
    gload16(ga0_ + (size_t)64 * LDA, As0 + (ss) * 4096 + wof + 2048);   \
    gload16(ga1_, As1 + (ss) * 4096 + wof);                            \
    gload16(ga1_ + (size_t)64 * LDA, As1 + (ss) * 4096 + wof + 2048);   \
    gload16(gb_, Bs + (ss) * 4096 + wof);                              \
    gload16(gb_ + (size_t)64 * LDB, Bs + (ss) * 4096 + wof + 2048);     \
  }

#define FRAGS3_(ss)                                                     \
  half8 af0[4], af1[4], bf[4];                                          \
  _Pragma("unroll") for (int n = 0; n < 4; ++n)                         \
      bf[n] = *(const half8*)(Bs + (ss) * 4096 +                        \
                              (wc * 64 + n * 16 + rl) * 32 + gsw);      \
  _Pragma("unroll") for (int m = 0; m < 4; ++m)                         \
      af0[m] = *(const half8*)(As0 + (ss) * 4096 +                      \
                               (wr * 64 + m * 16 + rl) * 32 + gsw);     \
  _Pragma("unroll") for (int m = 0; m < 4; ++m)                         \
      af1[m] = *(const half8*)(As1 + (ss) * 4096 +                      \
                               (wr * 64 + m * 16 + rl) * 32 + gsw);

#define MFMA32_                                                         \
  __builtin_amdgcn_s_setprio(1);                                        \
  _Pragma("unroll") for (int m = 0; m < 4; ++m)                         \
      _Pragma("unroll") for (int n = 0; n < 4; ++n)                     \
          acc0[m][n] = __builtin_amdgcn_mfma_f32_16x16x32_f16(          \
              af0[m], bf[n], acc0[m][n], 0, 0, 0);                      \
  _Pragma("unroll") for (int m = 0; m < 4; ++m)                         \
      _Pragma("unroll") for (int n = 0; n < 4; ++n)                     \
          acc1[m][n] = __builtin_amdgcn_mfma_f32_16x16x32_f16(          \
              af1[m], bf[n], acc1[m][n], 0, 0, 0);                      \
  __builtin_amdgcn_s_setprio(0);

#define STEPF_(ss, kt)                                                  \
  asm volatile("s_waitcnt vmcnt(6)" ::: "memory");                      \
  __builtin_amdgcn_s_barrier();                                         \
  __builtin_amdgcn_sched_barrier(0);                                    \
  STG3_(((ss) + 2) % 3, (kt) + 2);                                      \
  { FRAGS3_(ss) MFMA32_ }

#define STEPL6_(ss)                                                     \
  asm volatile("s_waitcnt vmcnt(6)" ::: "memory");                      \
  __builtin_amdgcn_s_barrier();                                         \
  __builtin_amdgcn_sched_barrier(0);                                    \
  { FRAGS3_(ss) MFMA32_ }

#define STEPL0_(ss)                                                     \
  asm volatile("s_waitcnt vmcnt(0)" ::: "memory");                      \
  __builtin_amdgcn_s_barrier();                                         \
  __builtin_amdgcn_sched_barrier(0);                                    \
  { FRAGS3_(ss) MFMA32_ }

  STG3_(0, 0);
  STG3_(1, 1);
  const int nTrip = ksteps / 3;
  for (int u = 0; u < nTrip - 1; ++u) {
    const int kt = 3 * u;
    STEPF_(0, kt);
    STEPF_(1, kt + 1);
    STEPF_(2, kt + 2);
  }
  STEPF_(0, ksteps - 3);
  STEPL6_(1);
  STEPL0_(2);
#undef STG3_
#undef FRAGS3_
#undef MFMA32_
#undef STEPF_
#undef STEPL6_
#undef STEPL0_
}

// K4: sims[bk][i] += sum_j relu(content[bk] @ Wg[b]^T). grid (8,4,32)
__global__ __launch_bounds__(256, 2) void k_sims(const u16* __restrict__ cbf,
                                                 const u16* __restrict__ Wg,
                                                 float* __restrict__ sims) {
  __shared__ __align__(16) u16 As0[3 * 4096];
  __shared__ __align__(16) u16 As1[3 * 4096];
  __shared__ __align__(16) u16 Bs[3 * 4096];
  const int bk = blockIdx.z, b = bk >> 4;
  const int t = threadIdx.x;
  const int i0 = blockIdx.y * 256;
  const u16* A0 = cbf + (size_t)bk * SEQ * DIM + (size_t)i0 * DIM;
  const u16* A1 = A0 + (size_t)128 * DIM;
  const u16* B = Wg + (size_t)b * SEQ * DIM + (size_t)(blockIdx.x * 128) * DIM;
  f32x4 acc0[4][4] = {}, acc1[4][4] = {};
  gemm_ring2<DIM, DIM>(A0, A1, B, DIM / 32, As0, As1, Bs, acc0, acc1, t);
  const int lane = t & 63, w = t >> 6, wr = w >> 1;
  const int rg = lane >> 4, cl = lane & 15;
#pragma unroll
  for (int m = 0; m < 4; ++m) {
#pragma unroll
    for (int r = 0; r < 4; ++r) {
      float s0 = 0.f, s1 = 0.f;
#pragma unroll
      for (int n = 0; n < 4; ++n) {
        s0 += fmaxf(acc0[m][n][r], 0.f);
        s1 += fmaxf(acc1[m][n][r], 0.f);
      }
      s0 += __shfl_xor(s0, 1); s1 += __shfl_xor(s1, 1);
      s0 += __shfl_xor(s0, 2); s1 += __shfl_xor(s1, 2);
      s0 += __shfl_xor(s0, 4); s1 += __shfl_xor(s1, 4);
      s0 += __shfl_xor(s0, 8); s1 += __shfl_xor(s1, 8);
      if (cl == 0) {
        const int i = i0 + wr * 64 + m * 16 + rg * 4 + r;
        atomicAdd(&sims[(size_t)bk * SEQ + i], s0);
        atomicAdd(&sims[(size_t)bk * SEQ + i + 128], s1);
      }
    }
  }
}

// K5: wtsT[bk][j] = cw*score + (1-score). grid (4,32), block 256
__global__ void k_weights(const float* __restrict__ sims, const int* __restrict__ ids,
                          const float* __restrict__ cw, float* __restrict__ wtsT) {
  const int j = blockIdx.x * 256 + threadIdx.x;
  const int bk = blockIdx.y;
  const int b = bk >> 4, k = bk & 15;
  const float sm = sims[(size_t)bk * SEQ + j];
  float score = 1.f / (1.f + __expf(0.1f * sm - 6.f));  // sigmoid(-0.1*s + 6)
  score *= 1.f + (float)j * 0.01f;
  const int id = ids[b * SEQ + j];
  const float c = cw[(size_t)id * NV + k];
  wtsT[(size_t)bk * SEQ + j] = c * score + (1.f - score);
}

// K6: ctxw[bk][i][j] = f16(ctx * wtsT[bk][j]). grid 32768, block 256
__global__ void k_ctx(const float* __restrict__ ctx, const float* __restrict__ wtsT,
                      u16* __restrict__ ctxw) {
  const size_t i = ((size_t)blockIdx.x * 256 + threadIdx.x) * 4;
  const float4 c = *(const float4*)(ctx + i);
  const size_t bk = i >> 20;           // / (SEQ*SEQ)
  const int j = (int)(i & (SEQ - 1));  // column within row
  const float4 wv = *(const float4*)(wtsT + bk * SEQ + j);
  *(uint2*)(ctxw + i) =
      make_uint2(pk2h(c.x * wv.x, c.y * wv.y), pk2h(c.z * wv.z, c.w * wv.w));
}

// K7: hidden partials. grid (6, 8, 8): x=d-tile, y=i-tile, z=b*4+g
// Now on the single-A counted-vmcnt ring core.
__global__ __launch_bounds__(256, 2) void k_hidden(const u16* __restrict__ ctxw,
                                                   const u16* __restrict__ cT,
                                                   float* __restrict__ part) {
  __shared__ __align__(16) u16 As[3 * 4096];
  __shared__ __align__(16) u16 Bs[3 * 4096];
  const int z = blockIdx.z;
  const int b = z >> 2, g = z & 3;
  const int i0 = blockIdx.y * 128, d0 = blockIdx.x * 128;
  const int t = threadIdx.x;
  f32x4 acc[4][4] = {};
  for (int kk = 0; kk < 4; ++kk) {
    const int sense = g * 4 + kk;
    const u16* A = ctxw + ((size_t)(b * NV + sense) * SEQ + i0) * SEQ;
    const u16* B = cT + ((size_t)(b * NV + sense) * DIM + d0) * SEQ;
    gemm_ring1<SEQ, SEQ>(A, B, As, Bs, acc, t);
    __syncthreads();  // all reads of slots done before next call's prologue
  }
  const int lane = t & 63, w = t >> 6, wr = w >> 1, wc = w & 1;
  const int rg = lane >> 4, cl = lane & 15;
  float* P = part + ((size_t)(g * BSZ + b) * SEQ + i0) * DIM + d0;
#pragma unroll
  for (int m = 0; m < 4; ++m)
#pragma unroll
    for (int n = 0; n < 4; ++n)
#pragma unroll
      for (int r = 0; r < 4; ++r)
        P[(size_t)(wr * 64 + m * 16 + rg * 4 + r) * DIM + wc * 64 + n * 16 + cl] =
            acc[m][n][r];
}

// K8: hid = f16(sum_g part[g]). grid 1536, block 256
__global__ void k_reduce(const float* __restrict__ part, u16* __restrict__ hid) {
  const size_t i = ((size_t)blockIdx.x * 256 + threadIdx.x) * 4;
  const size_t NHID = (size_t)BSZ * SEQ * DIM;
  float4 s = {0.f, 0.f, 0.f, 0.f};
#pragma unroll
  for (int g = 0; g < 4; ++g) {
    const float4 p = *(const float4*)(part + (size_t)g * NHID + i);
    s.x += p.x; s.y += p.y; s.z += p.z; s.w += p.w;
  }
  *(uint2*)(hid + i) = make_uint2(pk2h(s.x, s.y), pk2h(s.z, s.w));
}

// ---------------------------------------------------------------------------
// K9: logits = hid @ Wb^T — 256x256, BK=32 slices (24), 8 slots x 16 KB ring,
// distance-3 staging, counted vmcnt (8/8/.../4/0), m201-style fine phases:
// per slice: {8 ds_read | STG_A | bar | lgkm(0) | 16 MFMA | bar}
//            {4 ds_read | STG_B | bar | lgkm(0) | 16 MFMA | vmcnt | bar}
// Slot-overwrite safety: each wave's lgkm(0) precedes the final barrier a
// STG follows, so all reads of the overwritten slot are complete. Granule
// swizzle g^=(row>>1)&3 on BOTH staged source and frag read (0 conflicts).
// Grid 1576 = 8 i-tiles x 197 v-tiles (vt=196 clamped; overlap rows
// recompute identical values — benign). XCD-swizzled. Plain stores.
__global__ __launch_bounds__(512, 2) void k_logits(const u16* __restrict__ hid,
                                                   const u16* __restrict__ Wb,
                                                   float* __restrict__ out) {
  __shared__ __align__(16) u16 lds[8 * 8192];  // 128 KB
  const int bid = blockIdx.x;
  const int swz = (bid & 7) * 197 + (bid >> 3);
  const int it = swz & 7, vt = swz >> 3;
  const int i0 = it * 256;
  const int v0 = (vt == 196) ? (VOCP - 256) : vt * 256;
  const int t = threadIdx.x;
  const int lane = t & 63, w = t >> 6;
  const int wm = w >> 2, wn = w & 3;
  const int rl = lane & 15, kg = lane >> 4;
  const int gsw = (kg ^ ((rl >> 1) & 3)) * 8;          // frag read granule
  const int srow = t >> 2;                             // staging row 0..127
  const int sgr = ((t & 3) ^ ((srow >> 1) & 3)) * 8;   // pre-swizzled src
  const u16* Abase = hid + (size_t)i0 * DIM;
  const u16* Bbase = Wb + (size_t)v0 * DIM;
  u16* ldst = lds + w * 512 + lane * 8;

#define STG(slot, base, koff)                                         \
  {                                                                   \
    const u16* s_ = (base) + (size_t)srow * DIM + (koff) + sgr;       \
    gload16(s_, ldst + (slot) * 8192);                                \
    gload16(s_ + (size_t)128 * DIM, ldst + (slot) * 8192 + 4096);     \
  }

#define SCHED0 __builtin_amdgcn_sched_barrier(0)
#define VM8 asm volatile("s_waitcnt vmcnt(8)" ::: "memory")
#define VM4 asm volatile("s_waitcnt vmcnt(4)" ::: "memory")
#define VM0 asm volatile("s_waitcnt vmcnt(0)" ::: "memory")
#define VMX
#define LGKM0 asm volatile("s_waitcnt lgkmcnt(0)" ::: "memory"); SCHED0

#define RD_BF(sB)                                                     \
  _Pragma("unroll") for (int n = 0; n < 4; ++n)                       \
      bf[n] = *(const half8*)(lds + (sB) * 8192 +                     \
                              (wn * 64 + n * 16 + rl) * 32 + gsw);
#define RD_AF(sA, mo)                                                 \
  _Pragma("unroll") for (int m = 0; m < 4; ++m)                       \
      af[m] = *(const half8*)(lds + (sA) * 8192 +                     \
                              (wm * 128 + ((mo) + m) * 16 + rl) * 32 + gsw);
#define MF16(mo)                                                      \
  __builtin_amdgcn_s_setprio(1);                                      \
  _Pragma("unroll") for (int m = 0; m < 4; ++m)                       \
      _Pragma("unroll") for (int n = 0; n < 4; ++n)                   \
          acc[(mo) + m][n] = __builtin_amdgcn_mfma_f32_16x16x32_f16(  \
              af[m], bf[n], acc[(mo) + m][n], 0, 0, 0);               \
  __builtin_amdgcn_s_setprio(0);

#define SLICE(sA, sB, stA, stB, koff, VMW)                            \
  {                                                                   \
    half8 af[4], bf[4];                                               \
    RD_BF(sB); RD_AF(sA, 0);                                          \
    STG(stA, Abase, koff);                                            \
    SCHED0; __builtin_amdgcn_s_barrier();                             \
    LGKM0; MF16(0);                                                   \
    SCHED0; __builtin_amdgcn_s_barrier();                             \
    RD_AF(sA, 4);                                                     \
    STG(stB, Bbase, koff);                                            \
    SCHED0; __builtin_amdgcn_s_barrier();                             \
    LGKM0; MF16(4);                                                   \
    VMW;                                                              \
    SCHED0; __builtin_amdgcn_s_barrier();                             \
  }

#define SLICE_NS(sA, sB, VMW)                                         \
  {                                                                   \
    half8 af[4], bf[4];                                               \
    RD_BF(sB); RD_AF(sA, 0);                                          \
    SCHED0; __builtin_amdgcn_s_barrier();                             \
    LGKM0; MF16(0);                                                   \
    SCHED0; __builtin_amdgcn_s_barrier();                             \
    RD_AF(sA, 4);                                                     \
    SCHED0; __builtin_amdgcn_s_barrier();                             \
    LGKM0; MF16(4);                                                   \
    VMW;                                                              \
    SCHED0; __builtin_amdgcn_s_barrier();                             \
  }

  f32x4 acc[8][4] = {};
  // prologue: slices 0,1,2 (A+B each); slotA(s)=2s, slotB(s)=2s+1 (mod 8)
  STG(0, Abase, 0);
  STG(1, Bbase, 0);
  STG(2, Abase, 32);
  STG(3, Bbase, 32);
  STG(4, Abase, 64);
  STG(5, Bbase, 64);
  VM8;                          // slice 0 landed (8 newer in flight)
  __builtin_amdgcn_s_barrier(); // visible to all waves
  SCHED0;

#pragma unroll 1
  for (int g = 0; g < 5; ++g) {  // slices 0..19, all stage slice+3
    const int kb = g * 128;
    SLICE(0, 1, 6, 7, kb + 96, VM8);
    SLICE(2, 3, 0, 1, kb + 128, VM8);
    SLICE(4, 5, 2, 3, kb + 160, VM8);
    SLICE(6, 7, 4, 5, kb + 192, VM8);
  }
  SLICE(0, 1, 6, 7, 736, VM8);   // slice 20, stages slice 23
  SLICE_NS(2, 3, VM4);           // slice 21
  SLICE_NS(4, 5, VM0);           // slice 22
  SLICE_NS(6, 7, VMX);           // slice 23
#undef STG
#undef SLICE
#undef SLICE_NS
#undef RD_BF
#undef RD_AF
#undef MF16
#undef LGKM0
#undef VM8
#undef VM4
#undef VM0
#undef VMX
#undef SCHED0

  // epilogue: C col = lane&15 (v), row = (lane>>4)*4 + r (i)
#pragma unroll
  for (int m = 0; m < 8; ++m)
#pragma unroll
    for (int n = 0; n < 4; ++n) {
      const int vv = v0 + wn * 64 + n * 16 + rl;
      if (vv < VOC) {
        const int ib = i0 + wm * 128 + m * 16 + kg * 4;
#pragma unroll
        for (int r = 0; r < 4; ++r)
          out[(size_t)(ib + r) * VOC + vv] = acc[m][n][r];
      }
    }
}

// ---------------------------------------------------------------------------
extern "C" void kernel_launch(void* const* d_in, const int* in_sizes, int n_in,
                              void* d_out, int out_size, void* d_ws, size_t ws_size,
                              hipStream_t stream) {
  const int* ids = (const int*)d_in[0];
  const float* content = (const float*)d_in[1];
  const float* ctx = (const float*)d_in[2];
  const float* W = (const float*)d_in[3];
  const float* cw = (const float*)d_in[4];
  float* out = (float*)d_out;
  char* ws = (char*)d_ws;

  // workspace layout (bytes, all 256-aligned); total 248,446,976
  u16* cbf  = (u16*)(ws);                  // 50,331,648  [32][S][D] f16
  u16* cT   = (u16*)(ws + 50331648);       // 50,331,648  [32][D][S] f16
  u16* Wb   = (u16*)(ws + 100663296);      // 77,266,944  [VOCP][D] f16
  u16* Wg   = (u16*)(ws + 177930240);      //  3,145,728  [B][S][D] f16
  u16* ctxw = (u16*)(ws + 181075968);      // 67,108,864  [32][S][S] f16
  float* sims = (float*)(ws + 248184832);  //    131,072  [32][S] f32
  float* wtsT = (float*)(ws + 248315904);  //    131,072  [32][S] f32
  // aliases (safe by dataflow: source buffer dead before alias first written)
  float* part = (float*)cbf;               // 25,165,824  [4][B][S][D] f32
  u16* hid = Wg;                           //  3,145,728  [B*S][D] f16

  k_prep_content<<<dim3(DIM / 64, SEQ / 64, BSZ * NV), 256, 0, stream>>>(
      content, cbf, cT);
  k_prep_w<<<VOCP, 192, 0, stream>>>(W, Wb);
  k_gather<<<dim3(SEQ, BSZ), 192, 0, stream>>>(ids, Wb, Wg);
  k_zero<<<128, 256, 0, stream>>>(sims, BSZ * NV * SEQ);
  k_sims<<<dim3(8, 4, BSZ * NV), 256, 0, stream>>>(cbf, Wg, sims);
  k_weights<<<dim3(4, BSZ * NV), 256, 0, stream>>>(sims, ids, cw, wtsT);
  k_ctx<<<32768, 256, 0, stream>>>(ctx, wtsT, ctxw);
  k_hidden<<<dim3(6, 8, 8), 256, 0, stream>>>(ctxw, cT, part);
  k_reduce<<<1536, 256, 0, stream>>>(part, hid);
  k_logits<<<8 * 197, 512, 0, stream>>>(hid, Wb, out);
}

// Round 9
// 564.147 us; speedup vs baseline: 1.4098x; 1.0291x over previous
//
#include <hip/hip_runtime.h>
#include <cstdint>
#include <cstddef>

#define BSZ 2
#define NV 16
#define SEQ 1024
#define DIM 768
#define VOC 50257
#define VOCP 50304   // padded to multiple of 128

typedef unsigned int u32;
typedef unsigned short u16;
typedef _Float16 half8 __attribute__((ext_vector_type(8)));
typedef float f32x4 __attribute__((ext_vector_type(4)));

__device__ __forceinline__ u16 f2h(float f) {
  return __builtin_bit_cast(unsigned short, (_Float16)f);
}
__device__ __forceinline__ u32 pk2h(float a, float b) {
  return (u32)f2h(a) | ((u32)f2h(b) << 16);
}

// async global->LDS, 16B per lane; LDS dest = wave-uniform base + lane*16
__device__ __forceinline__ void gload16(const u16* g, u16* l) {
  __builtin_amdgcn_global_load_lds(
      (const __attribute__((address_space(1))) void*)g,
      (__attribute__((address_space(3))) void*)l, 16, 0, 0);
}

// ---------------------------------------------------------------------------
// K1: content f32 -> f16 (normal + transposed). 64x64 tiles, float4 loads.
// grid (12, 16, 32), block 256
__global__ void k_prep_content(const float* __restrict__ content,
                               u16* __restrict__ cbf, u16* __restrict__ cT) {
  __shared__ u16 tile[64][70];
  const int bk = blockIdx.z;
  const int d0 = blockIdx.x * 64, j0 = blockIdx.y * 64;
  const float* src = content + (size_t)bk * SEQ * DIM;
  u16* dst = cbf + (size_t)bk * SEQ * DIM;
  u16* dstT = cT + (size_t)bk * DIM * SEQ;
  const int c4 = (threadIdx.x & 15) * 4;  // d-local (x4)
  const int r0 = threadIdx.x >> 4;        // 0..15
#pragma unroll
  for (int it = 0; it < 4; ++it) {
    const int r = it * 16 + r0;           // j-local
    const float4 f = *(const float4*)(src + (size_t)(j0 + r) * DIM + d0 + c4);
    const u32 lo = pk2h(f.x, f.y), hi = pk2h(f.z, f.w);
    *(uint2*)(dst + (size_t)(j0 + r) * DIM + d0 + c4) = make_uint2(lo, hi);
    *(u32*)&tile[r][c4] = lo;
    *(u32*)&tile[r][c4 + 2] = hi;
  }
  __syncthreads();
#pragma unroll
  for (int it = 0; it < 4; ++it) {
    const int dd = it * 16 + r0;          // d-local
    const int j4 = c4;                    // j-local (x4)
    const u32 lo = (u32)tile[j4][dd] | ((u32)tile[j4 + 1][dd] << 16);
    const u32 hi = (u32)tile[j4 + 2][dd] | ((u32)tile[j4 + 3][dd] << 16);
    *(uint2*)(dstT + (size_t)(d0 + dd) * SEQ + j0 + j4) = make_uint2(lo, hi);
  }
}

// K2: lm_head_weight f32 -> f16, padded rows zeroed. grid VOCP, block 192
__global__ void k_prep_w(const float* __restrict__ W, u16* __restrict__ Wb) {
  const int v = blockIdx.x;
  const int c = threadIdx.x * 4;
  u32 lo, hi;
  if (v < VOC) {
    const float4 f = *(const float4*)(W + (size_t)v * DIM + c);
    lo = pk2h(f.x, f.y); hi = pk2h(f.z, f.w);
  } else {
    lo = 0u; hi = 0u;
  }
  *(uint2*)(Wb + (size_t)v * DIM + c) = make_uint2(lo, hi);
}

// K3: gather Wg[b][j][:] = Wb[ids[b][j]][:]  grid (SEQ, BSZ), block 192
__global__ void k_gather(const int* __restrict__ ids, const u16* __restrict__ Wb,
                         u16* __restrict__ Wg) {
  const int b = blockIdx.y, j = blockIdx.x;
  const int row = ids[b * SEQ + j];
  const int c = threadIdx.x * 4;
  *(uint2*)(Wg + ((size_t)b * SEQ + j) * DIM + c) =
      *(const uint2*)(Wb + (size_t)row * DIM + c);
}

__global__ void k_zero(float* __restrict__ p, int n) {
  const int i = blockIdx.x * 256 + threadIdx.x;
  if (i < n) p[i] = 0.f;
}

// ---------------------------------------------------------------------------
// Single-A ring core: 128x128 tile, 3-slot LDS ring, distance-2 prefetch,
// counted vmcnt(4) (never 0 mid-loop). ksteps = 32 fixed (SEQ/32).
template <int LDA, int LDB>
__device__ __forceinline__ void gemm_ring1(const u16* __restrict__ A,
                                           const u16* __restrict__ B,
                                           u16* As, u16* Bs,
                                           f32x4 (&acc)[4][4], int t) {
  const int lane = t & 63, w = t >> 6, wr = w >> 1, wc = w & 1;
  const int rl = lane & 15;
  const int gsw = (((lane >> 4) ^ ((rl >> 1) & 3)) * 8);
  const int srow = 16 * w + (lane >> 2);
  const int sg = (((lane & 3) ^ ((lane >> 3) & 3)) * 8);
  const size_t gaBase = (size_t)srow * LDA + sg;
  const size_t gbBase = (size_t)srow * LDB + sg;
  const int wof = w * 512;

#define STG1_(ss, kt)                                                   \
  {                                                                     \
    const u16* ga_ = A + gaBase + (size_t)(kt) * 32;                    \
    const u16* gb_ = B + gbBase + (size_t)(kt) * 32;                    \
    gload16(ga_, As + (ss) * 4096 + wof);                               \
    gload16(ga_ + (size_t)64 * LDA, As + (ss) * 4096 + wof + 2048);     \
    gload16(gb_, Bs + (ss) * 4096 + wof);                               \
    gload16(gb_ + (size_t)64 * LDB, Bs + (ss) * 4096 + wof + 2048);     \
  }

  STG1_(0, 0);
  STG1_(1, 1);
#pragma unroll 1
  for (int kt = 0; kt < 32; ++kt) {
    if (kt < 31)
      asm volatile("s_waitcnt vmcnt(4)" ::: "memory");
    else
      asm volatile("s_waitcnt vmcnt(0)" ::: "memory");
    __builtin_amdgcn_s_barrier();
    __builtin_amdgcn_sched_barrier(0);
    const int ss = kt % 3;
    if (kt < 30) STG1_((kt + 2) % 3, kt + 2);
    half8 af[4], bf[4];
#pragma unroll
    for (int m = 0; m < 4; ++m)
      af[m] = *(const half8*)(As + ss * 4096 + (wr * 64 + m * 16 + rl) * 32 + gsw);
#pragma unroll
    for (int n = 0; n < 4; ++n)
      bf[n] = *(const half8*)(Bs + ss * 4096 + (wc * 64 + n * 16 + rl) * 32 + gsw);
    __builtin_amdgcn_s_setprio(1);
#pragma unroll
    for (int m = 0; m < 4; ++m)
#pragma unroll
      for (int n = 0; n < 4; ++n)
        acc[m][n] = __builtin_amdgcn_mfma_f32_16x16x32_f16(af[m], bf[n], acc[m][n], 0, 0, 0);
    __builtin_amdgcn_s_setprio(0);
  }
#undef STG1_
}

// ---------------------------------------------------------------------------
// Dual-A ring core (round-6, verified) — used by k_sims.
template <int LDA, int LDB>
__device__ __forceinline__ void gemm_ring2(const u16* __restrict__ A0,
                                           const u16* __restrict__ A1,
                                           const u16* __restrict__ B, int ksteps,
                                           u16* As0, u16* As1, u16* Bs,
                                           f32x4 (&acc0)[4][4],
                                           f32x4 (&acc1)[4][4], int t) {
  const int lane = t & 63, w = t >> 6, wr = w >> 1, wc = w & 1;
  const int rl = lane & 15;
  const int gsw = (((lane >> 4) ^ ((rl >> 1) & 3)) * 8);
  const int srow = 16 * w + (lane >> 2);
  const int sg = (((lane & 3) ^ ((lane >> 3) & 3)) * 8);
  const size_t gaBase = (size_t)srow * LDA + sg;
  const size_t gbBase = (size_t)srow * LDB + sg;
  const int wof = w * 512;

#define STG3_(ss, kt)                                                   \
  {                                                                     \
    const u16* ga0_ = A0 + gaBase + (size_t)(kt) * 32;                  \
    const u16* ga1_ = A1 + gaBase + (size_t)(kt) * 32;                  \
    const u16* gb_ = B + gbBase + (size_t)(kt) * 32;                    \
    gload16(ga0_, As0 + (ss) * 4096 + wof);                             \
    gload16(ga0_ + (size_t)64 * LDA, As0 + (ss) * 4096 + wof + 2048);   \
    gload16(ga1_, As1 + (ss) * 4096 + wof);                            \
    gload16(ga1_ + (size_t)64 * LDA, As1 + (ss) * 4096 + wof + 2048);   \
    gload16(gb_, Bs + (ss) * 4096 + wof);                              \
    gload16(gb_ + (size_t)64 * LDB, Bs + (ss) * 4096 + wof + 2048);     \
  }

#define FRAGS3_(ss)                                                     \
  half8 af0[4], af1[4], bf[4];                                          \
  _Pragma("unroll") for (int n = 0; n < 4; ++n)                         \
      bf[n] = *(const half8*)(Bs + (ss) * 4096 +                        \
                              (wc * 64 + n * 16 + rl) * 32 + gsw);      \
  _Pragma("unroll") for (int m = 0; m < 4; ++m)                         \
      af0[m] = *(const half8*)(As0 + (ss) * 4096 +                      \
                               (wr * 64 + m * 16 + rl) * 32 + gsw);     \
  _Pragma("unroll") for (int m = 0; m < 4; ++m)                         \
      af1[m] = *(const half8*)(As1 + (ss) * 4096 +                      \
                               (wr * 64 + m * 16 + rl) * 32 + gsw);

#define MFMA32_                                                         \
  __builtin_amdgcn_s_setprio(1);                                        \
  _Pragma("unroll") for (int m = 0; m < 4; ++m)                         \
      _Pragma("unroll") for (int n = 0; n < 4; ++n)                     \
          acc0[m][n] = __builtin_amdgcn_mfma_f32_16x16x32_f16(          \
              af0[m], bf[n], acc0[m][n], 0, 0, 0);                      \
  _Pragma("unroll") for (int m = 0; m < 4; ++m)                         \
      _Pragma("unroll") for (int n = 0; n < 4; ++n)                     \
          acc1[m][n] = __builtin_amdgcn_mfma_f32_16x16x32_f16(          \
              af1[m], bf[n], acc1[m][n], 0, 0, 0);                      \
  __builtin_amdgcn_s_setprio(0);

#define STEPF_(ss, kt)                                                  \
  asm volatile("s_waitcnt vmcnt(6)" ::: "memory");                      \
  __builtin_amdgcn_s_barrier();                                         \
  __builtin_amdgcn_sched_barrier(0);                                    \
  STG3_(((ss) + 2) % 3, (kt) + 2);                                      \
  { FRAGS3_(ss) MFMA32_ }

#define STEPL6_(ss)                                                     \
  asm volatile("s_waitcnt vmcnt(6)" ::: "memory");                      \
  __builtin_amdgcn_s_barrier();                                         \
  __builtin_amdgcn_sched_barrier(0);                                    \
  { FRAGS3_(ss) MFMA32_ }

#define STEPL0_(ss)                                                     \
  asm volatile("s_waitcnt vmcnt(0)" ::: "memory");                      \
  __builtin_amdgcn_s_barrier();                                         \
  __builtin_amdgcn_sched_barrier(0);                                    \
  { FRAGS3_(ss) MFMA32_ }

  STG3_(0, 0);
  STG3_(1, 1);
  const int nTrip = ksteps / 3;
  for (int u = 0; u < nTrip - 1; ++u) {
    const int kt = 3 * u;
    STEPF_(0, kt);
    STEPF_(1, kt + 1);
    STEPF_(2, kt + 2);
  }
  STEPF_(0, ksteps - 3);
  STEPL6_(1);
  STEPL0_(2);
#undef STG3_
#undef FRAGS3_
#undef MFMA32_
#undef STEPF_
#undef STEPL6_
#undef STEPL0_
}

// K4: sims[bk][i] += sum_j relu(content[bk] @ Wg[b]^T). grid (8,4,32)
__global__ __launch_bounds__(256, 2) void k_sims(const u16* __restrict__ cbf,
                                                 const u16* __restrict__ Wg,
                                                 float* __restrict__ sims) {
  __shared__ __align__(16) u16 As0[3 * 4096];
  __shared__ __align__(16) u16 As1[3 * 4096];
  __shared__ __align__(16) u16 Bs[3 * 4096];
  const int bk = blockIdx.z, b = bk >> 4;
  const int t = threadIdx.x;
  const int i0 = blockIdx.y * 256;
  const u16* A0 = cbf + (size_t)bk * SEQ * DIM + (size_t)i0 * DIM;
  const u16* A1 = A0 + (size_t)128 * DIM;
  const u16* B = Wg + (size_t)b * SEQ * DIM + (size_t)(blockIdx.x * 128) * DIM;
  f32x4 acc0[4][4] = {}, acc1[4][4] = {};
  gemm_ring2<DIM, DIM>(A0, A1, B, DIM / 32, As0, As1, Bs, acc0, acc1, t);
  const int lane = t & 63, w = t >> 6, wr = w >> 1;
  const int rg = lane >> 4, cl = lane & 15;
#pragma unroll
  for (int m = 0; m < 4; ++m) {
#pragma unroll
    for (int r = 0; r < 4; ++r) {
      float s0 = 0.f, s1 = 0.f;
#pragma unroll
      for (int n = 0; n < 4; ++n) {
        s0 += fmaxf(acc0[m][n][r], 0.f);
        s1 += fmaxf(acc1[m][n][r], 0.f);
      }
      s0 += __shfl_xor(s0, 1); s1 += __shfl_xor(s1, 1);
      s0 += __shfl_xor(s0, 2); s1 += __shfl_xor(s1, 2);
      s0 += __shfl_xor(s0, 4); s1 += __shfl_xor(s1, 4);
      s0 += __shfl_xor(s0, 8); s1 += __shfl_xor(s1, 8);
      if (cl == 0) {
        const int i = i0 + wr * 64 + m * 16 + rg * 4 + r;
        atomicAdd(&sims[(size_t)bk * SEQ + i], s0);
        atomicAdd(&sims[(size_t)bk * SEQ + i + 128], s1);
      }
    }
  }
}

// K5: wtsT[bk][j] = cw*score + (1-score). grid (4,32), block 256
__global__ void k_weights(const float* __restrict__ sims, const int* __restrict__ ids,
                          const float* __restrict__ cw, float* __restrict__ wtsT) {
  const int j = blockIdx.x * 256 + threadIdx.x;
  const int bk = blockIdx.y;
  const int b = bk >> 4, k = bk & 15;
  const float sm = sims[(size_t)bk * SEQ + j];
  float score = 1.f / (1.f + __expf(0.1f * sm - 6.f));  // sigmoid(-0.1*s + 6)
  score *= 1.f + (float)j * 0.01f;
  const int id = ids[b * SEQ + j];
  const float c = cw[(size_t)id * NV + k];
  wtsT[(size_t)bk * SEQ + j] = c * score + (1.f - score);
}

// K6: ctxw[bk][i][j] = f16(ctx * wtsT[bk][j]). grid 32768, block 256
__global__ void k_ctx(const float* __restrict__ ctx, const float* __restrict__ wtsT,
                      u16* __restrict__ ctxw) {
  const size_t i = ((size_t)blockIdx.x * 256 + threadIdx.x) * 4;
  const float4 c = *(const float4*)(ctx + i);
  const size_t bk = i >> 20;           // / (SEQ*SEQ)
  const int j = (int)(i & (SEQ - 1));  // column within row
  const float4 wv = *(const float4*)(wtsT + bk * SEQ + j);
  *(uint2*)(ctxw + i) =
      make_uint2(pk2h(c.x * wv.x, c.y * wv.y), pk2h(c.z * wv.z, c.w * wv.w));
}

// K7: hidden partials. grid (6, 8, 16): x=d-tile, y=i-tile, z=b*8+g
// (2 senses/group -> 768 blocks = EXACTLY 1.0 round at 3 blocks/CU, 12 w/CU)
__global__ __launch_bounds__(256, 3) void k_hidden(const u16* __restrict__ ctxw,
                                                   const u16* __restrict__ cT,
                                                   float* __restrict__ part) {
  __shared__ __align__(16) u16 As[3 * 4096];
  __shared__ __align__(16) u16 Bs[3 * 4096];
  const int z = blockIdx.z;
  const int b = z >> 3, g = z & 7;
  const int i0 = blockIdx.y * 128, d0 = blockIdx.x * 128;
  const int t = threadIdx.x;
  f32x4 acc[4][4] = {};
  for (int kk = 0; kk < 2; ++kk) {
    const int sense = g * 2 + kk;
    const u16* A = ctxw + ((size_t)(b * NV + sense) * SEQ + i0) * SEQ;
    const u16* B = cT + ((size_t)(b * NV + sense) * DIM + d0) * SEQ;
    gemm_ring1<SEQ, SEQ>(A, B, As, Bs, acc, t);
    __syncthreads();  // all reads of slots done before next call's prologue
  }
  const int lane = t & 63, w = t >> 6, wr = w >> 1, wc = w & 1;
  const int rg = lane >> 4, cl = lane & 15;
  float* P = part + ((size_t)(g * BSZ + b) * SEQ + i0) * DIM + d0;
#pragma unroll
  for (int m = 0; m < 4; ++m)
#pragma unroll
    for (int n = 0; n < 4; ++n)
#pragma unroll
      for (int r = 0; r < 4; ++r)
        P[(size_t)(wr * 64 + m * 16 + rg * 4 + r) * DIM + wc * 64 + n * 16 + cl] =
            acc[m][n][r];
}

// K8: hid = f16(sum_g part[g]), 8 groups. grid 1536, block 256
__global__ void k_reduce(const float* __restrict__ part, u16* __restrict__ hid) {
  const size_t i = ((size_t)blockIdx.x * 256 + threadIdx.x) * 4;
  const size_t NHID = (size_t)BSZ * SEQ * DIM;
  float4 s = {0.f, 0.f, 0.f, 0.f};
#pragma unroll
  for (int g = 0; g < 8; ++g) {
    const float4 p = *(const float4*)(part + (size_t)g * NHID + i);
    s.x += p.x; s.y += p.y; s.z += p.z; s.w += p.w;
  }
  *(uint2*)(hid + i) = make_uint2(pk2h(s.x, s.y), pk2h(s.z, s.w));
}

// ---------------------------------------------------------------------------
// K9: logits = hid @ Wb^T — 256(i) x 128(v) tile, 256 thr (4 waves, 2M x 2N,
// 128x64 out/wave = 8x4 frags). 3-slice LDS ring (72 KB: A 16KB + B 8KB per
// slice) -> 2 blocks/CU (144 KB), distance-2 prefetch, counted vmcnt(6)
// (6 gloads/slice; never drains mid-loop). Slot-overwrite safety identical to
// round-6 proof: STG(k+2) issued after barrier_k overwrites slot (k+2)%3 =
// (k-1)%3, whose reads completed before barrier_k in every wave. Granule
// swizzle g ^= (row>>1)&3 on BOTH staged src and frag read (0 conflicts).
// Grid 3144 = 8 i-tiles x 393 v-tiles (VOCP = 393*128 exact). XCD-swizzled
// (3144 % 8 == 0). Plain stores (NT amplified writes 2x in round 4).
__global__ __launch_bounds__(256, 2) void k_logits(const u16* __restrict__ hid,
                                                   const u16* __restrict__ Wb,
                                                   float* __restrict__ out) {
  __shared__ __align__(16) u16 lds[3 * 12288];  // per slice: A 8192 + B 4096 u16
  const int bid = blockIdx.x;
  const int swz = (bid & 7) * 393 + (bid >> 3);
  const int it = swz & 7, vt = swz >> 3;
  const int i0 = it * 256, v0 = vt * 128;
  const int t = threadIdx.x;
  const int lane = t & 63, w = t >> 6;
  const int wm = w >> 1, wn = w & 1;
  const int rl = lane & 15, kg = lane >> 4;
  const int gsw = (kg ^ ((rl >> 1) & 3)) * 8;          // frag read granule
  const int srow = t >> 2;                             // staging row 0..63
  const int sgr = ((t & 3) ^ ((srow >> 1) & 3)) * 8;   // pre-swizzled src
  // (row = c*64 + srow: (row>>1)&3 == (srow>>1)&3 since 64|c*64; read row =
  //  wm*128 + m*16 + rl: (row>>1)&3 == (rl>>1)&3 — involution matches.)
  const u16* Abase = hid + ((size_t)i0 + srow) * DIM + sgr;
  const u16* Bbase = Wb + ((size_t)v0 + srow) * DIM + sgr;
  u16* dls = lds + t * 8;

#define STG(ss, koff)                                                 \
  {                                                                   \
    const u16* a_ = Abase + (koff);                                   \
    u16* d_ = dls + (ss) * 12288;                                     \
    gload16(a_, d_);                                                  \
    gload16(a_ + (size_t)64 * DIM, d_ + 2048);                        \
    gload16(a_ + (size_t)128 * DIM, d_ + 4096);                       \
    gload16(a_ + (size_t)192 * DIM, d_ + 6144);                       \
    const u16* b_ = Bbase + (koff);                                   \
    gload16(b_, d_ + 8192);                                           \
    gload16(b_ + (size_t)64 * DIM, d_ + 10240);                       \
  }

#define CMP(ss)                                                       \
  {                                                                   \
    half8 af[8], bf[4];                                               \
    _Pragma("unroll") for (int n = 0; n < 4; ++n)                     \
        bf[n] = *(const half8*)(lds + (ss) * 12288 + 8192 +           \
                                (wn * 64 + n * 16 + rl) * 32 + gsw);  \
    _Pragma("unroll") for (int m = 0; m < 8; ++m)                     \
        af[m] = *(const half8*)(lds + (ss) * 12288 +                  \
                                (wm * 128 + m * 16 + rl) * 32 + gsw); \
    __builtin_amdgcn_s_setprio(1);                                    \
    _Pragma("unroll") for (int m = 0; m < 8; ++m)                     \
        _Pragma("unroll") for (int n = 0; n < 4; ++n)                 \
            acc[m][n] = __builtin_amdgcn_mfma_f32_16x16x32_f16(       \
                af[m], bf[n], acc[m][n], 0, 0, 0);                    \
    __builtin_amdgcn_s_setprio(0);                                    \
  }

#define BARS                                                          \
  __builtin_amdgcn_s_barrier();                                       \
  __builtin_amdgcn_sched_barrier(0);

#define STEPF(ss, st, koff)                                           \
  asm volatile("s_waitcnt vmcnt(6)" ::: "memory");                    \
  BARS;                                                               \
  STG(st, koff);                                                      \
  CMP(ss)

  f32x4 acc[8][4] = {};
  STG(0, 0);
  STG(1, 32);
#pragma unroll 1
  for (int u = 0; u < 7; ++u) {
    const int kb = u * 96;
    STEPF(0, 2, kb + 64);    // slice 3u,   stage 3u+2
    STEPF(1, 0, kb + 96);    // slice 3u+1, stage 3u+3
    STEPF(2, 1, kb + 128);   // slice 3u+2, stage 3u+4
  }
  STEPF(0, 2, 736);          // slice 21, stage 23
  asm volatile("s_waitcnt vmcnt(6)" ::: "memory");  // slice 22 landed
  BARS;
  CMP(1);
  asm volatile("s_waitcnt vmcnt(0)" ::: "memory");  // slice 23 landed
  BARS;
  CMP(2);
#undef STG
#undef CMP
#undef BARS
#undef STEPF

  // epilogue: C col = lane&15 (v), row = (lane>>4)*4 + r (i)
#pragma unroll
  for (int m = 0; m < 8; ++m)
#pragma unroll
    for (int n = 0; n < 4; ++n) {
      const int vv = v0 + wn * 64 + n * 16 + rl;
      if (vv < VOC) {
        const int ib = i0 + wm * 128 + m * 16 + kg * 4;
#pragma unroll
        for (int r = 0; r < 4; ++r)
          out[(size_t)(ib + r) * VOC + vv] = acc[m][n][r];
      }
    }
}

// ---------------------------------------------------------------------------
extern "C" void kernel_launch(void* const* d_in, const int* in_sizes, int n_in,
                              void* d_out, int out_size, void* d_ws, size_t ws_size,
                              hipStream_t stream) {
  const int* ids = (const int*)d_in[0];
  const float* content = (const float*)d_in[1];
  const float* ctx = (const float*)d_in[2];
  const float* W = (const float*)d_in[3];
  const float* cw = (const float*)d_in[4];
  float* out = (float*)d_out;
  char* ws = (char*)d_ws;

  // workspace layout (bytes, all 256-aligned); total 248,446,976
  u16* cbf  = (u16*)(ws);                  // 50,331,648  [32][S][D] f16
  u16* cT   = (u16*)(ws + 50331648);       // 50,331,648  [32][D][S] f16
  u16* Wb   = (u16*)(ws + 100663296);      // 77,266,944  [VOCP][D] f16
  u16* Wg   = (u16*)(ws + 177930240);      //  3,145,728  [B][S][D] f16
  u16* ctxw = (u16*)(ws + 181075968);      // 67,108,864  [32][S][S] f16
  float* sims = (float*)(ws + 248184832);  //    131,072  [32][S] f32
  float* wtsT = (float*)(ws + 248315904);  //    131,072  [32][S] f32
  // aliases (safe by dataflow: source buffer dead before alias first written)
  float* part = (float*)cbf;               // 50,331,648  [8][B][S][D] f32
  u16* hid = Wg;                           //  3,145,728  [B*S][D] f16

  k_prep_content<<<dim3(DIM / 64, SEQ / 64, BSZ * NV), 256, 0, stream>>>(
      content, cbf, cT);
  k_prep_w<<<VOCP, 192, 0, stream>>>(W, Wb);
  k_gather<<<dim3(SEQ, BSZ), 192, 0, stream>>>(ids, Wb, Wg);
  k_zero<<<128, 256, 0, stream>>>(sims, BSZ * NV * SEQ);
  k_sims<<<dim3(8, 4, BSZ * NV), 256, 0, stream>>>(cbf, Wg, sims);
  k_weights<<<dim3(4, BSZ * NV), 256, 0, stream>>>(sims, ids, cw, wtsT);
  k_ctx<<<32768, 256, 0, stream>>>(ctx, wtsT, ctxw);
  k_hidden<<<dim3(6, 8, 16), 256, 0, stream>>>(ctxw, cT, part);
  k_reduce<<<1536, 256, 0, stream>>>(part, hid);
  k_logits<<<8 * 393, 256, 0, stream>>>(hid, Wb, out);
}